// Round 8
// baseline (293.700 us; speedup 1.0000x reference)
//
#include <hip/hip_runtime.h>
#include <math.h>

// GAT 2-layer, N=100K nodes, E=1.6M edges (+N self loops), fp32 compute,
// f16 feature rows for the edge gather.
// CSR build via 2-level bucket sort (bucket = dst>>8).
// agg: 8 lanes per dst node, 8 nodes per wave, octet unroll, f16 pair-dot.
//   h tables: [N][64] f16 = 128B-ALIGNED rows, exactly one L2 line per edge.
//   r8: L2-line-granularity lesson -- r6 (80B) and r7 (64B+16B split) both
//   RAISED fetch (88->95->97MB): misses pull whole 128B lines, so sub-line
//   row compaction only adds line-touches. Reverted to r5 layout.
//   r8 NEW: nontemporal stores for all streamed outputs + NT csr loads --
//   keep the 4MB/XCD L2 free for the random h-row gather working set.
// gemm1 MFMA 3-pass truncation-split bf16, x staged via coalesced LDS.

constexpr int F_IN = 128;
constexpr int F_H  = 64;
constexpr int F_O  = 40;
constexpr int NBMAX = 512;      // max buckets (N <= 131072)
constexpr int CHUNK = 8192;     // edges per block in k_binC

using h2 = decltype(__builtin_amdgcn_cvt_pkrtz(0.f, 0.f));   // <2 x half>
typedef __attribute__((ext_vector_type(4))) float f32x4;
typedef __attribute__((ext_vector_type(8))) short s16x8;

__device__ __forceinline__ h2 u2h(unsigned u) { return __builtin_bit_cast(h2, u); }

__device__ __forceinline__ float fdot2f(h2 a, h2 b, float c) {
#if __has_builtin(__builtin_amdgcn_fdot2)
    return __builtin_amdgcn_fdot2(a, b, c, false);      // v_dot2_f32_f16
#else
    return c + (float)a.x * (float)b.x + (float)a.y * (float)b.y;
#endif
}
// interleave two u32s of packed f16 pairs: pklo -> (b.lo16, a.lo16), pkhi -> (b.hi16, a.hi16)
__device__ __forceinline__ h2 pklo(unsigned a, unsigned b) {
    return u2h(__builtin_amdgcn_perm(a, b, 0x05040100u));
}
__device__ __forceinline__ h2 pkhi(unsigned a, unsigned b) {
    return u2h(__builtin_amdgcn_perm(a, b, 0x07060302u));
}
__device__ __forceinline__ unsigned short f2h(float f) {   // RNE f32->f16 bits
    _Float16 x = (_Float16)f;
    return __builtin_bit_cast(unsigned short, x);
}
__device__ __forceinline__ void nt_store4(uint4* p, uint4 v) {
    __builtin_nontemporal_store(v.x, &p->x);
    __builtin_nontemporal_store(v.y, &p->y);
    __builtin_nontemporal_store(v.z, &p->z);
    __builtin_nontemporal_store(v.w, &p->w);
}
__device__ __forceinline__ void nt_storef4(float4* p, float4 v) {
    __builtin_nontemporal_store(v.x, &p->x);
    __builtin_nontemporal_store(v.y, &p->y);
    __builtin_nontemporal_store(v.z, &p->z);
    __builtin_nontemporal_store(v.w, &p->w);
}

// ---------------- CSR build: bucket sort ----------------

__global__ __launch_bounds__(256) void k_binA(const int* __restrict__ dsts,
                                              int* __restrict__ bcnt,
                                              int E, int Et, int NB) {
    __shared__ int hist[NBMAX];
    for (int i = threadIdx.x; i < NB; i += 256) hist[i] = 0;
    __syncthreads();
    int e0 = blockIdx.x * 2048;
#pragma unroll
    for (int it = 0; it < 8; ++it) {
        int e = e0 + it * 256 + threadIdx.x;
        if (e < Et) {
            int d = (e < E) ? dsts[e] : (e - E);
            atomicAdd(&hist[d >> 8], 1);
        }
    }
    __syncthreads();
    for (int i = threadIdx.x; i < NB; i += 256) {
        int c = hist[i];
        if (c) atomicAdd(&bcnt[i], c);
    }
}

__global__ __launch_bounds__(NBMAX) void k_binB(const int* __restrict__ bcnt,
                                                int* __restrict__ bbase,
                                                int* __restrict__ bcur,
                                                int* __restrict__ rp,
                                                int NB, int N, int Et) {
    __shared__ int sc[NBMAX];
    int t = threadIdx.x;
    int v = (t < NB) ? bcnt[t] : 0;
    sc[t] = v; __syncthreads();
    int x = v;
    for (int o = 1; o < NBMAX; o <<= 1) {
        int y = (t >= o) ? sc[t - o] : 0;
        __syncthreads();
        x += y;
        sc[t] = x;
        __syncthreads();
    }
    if (t < NB) { int b = x - v; bbase[t] = b; bcur[t] = b; }
    if (t == 0) rp[N] = Et;
}

__global__ __launch_bounds__(256) void k_binC(const int* __restrict__ srcs,
                                              const int* __restrict__ dsts,
                                              int* __restrict__ bcur,
                                              unsigned* __restrict__ binned,
                                              int E, int Et, int NB) {
    __shared__ int hist[NBMAX];
    __shared__ int gbase[NBMAX];
    __shared__ int lcnt[NBMAX];
    int t = threadIdx.x;
    for (int i = t; i < NB; i += 256) hist[i] = 0;
    __syncthreads();
    int e0 = blockIdx.x * CHUNK;
#pragma unroll 4
    for (int it = 0; it < CHUNK / 256; ++it) {
        int e = e0 + it * 256 + t;
        if (e < Et) {
            int d = (e < E) ? dsts[e] : (e - E);
            atomicAdd(&hist[d >> 8], 1);
        }
    }
    __syncthreads();
    for (int i = t; i < NB; i += 256) {
        int c = hist[i];
        gbase[i] = c ? atomicAdd(&bcur[i], c) : 0;
        lcnt[i] = 0;
    }
    __syncthreads();
#pragma unroll 4
    for (int it = 0; it < CHUNK / 256; ++it) {
        int e = e0 + it * 256 + t;
        if (e < Et) {
            int s, d;
            if (e < E) { s = srcs[e]; d = dsts[e]; } else { s = e - E; d = s; }
            int b = d >> 8;
            int p = atomicAdd(&lcnt[b], 1);
            binned[gbase[b] + p] = (unsigned)s | ((unsigned)(d & 255) << 24);
        }
    }
}

__global__ __launch_bounds__(256) void k_binD(const unsigned* __restrict__ binned,
                                              const int* __restrict__ bbase,
                                              const int* __restrict__ bcur,
                                              int* __restrict__ rp,
                                              int* __restrict__ csr, int N) {
    __shared__ int hist[256];
    __shared__ int sc[256];
    __shared__ int lcnt[256];
    int b = blockIdx.x, t = threadIdx.x;
    int base = bbase[b], end = bcur[b];
    hist[t] = 0; __syncthreads();
    for (int j = base + t; j < end; j += 256)
        atomicAdd(&hist[binned[j] >> 24], 1);
    __syncthreads();
    int v = hist[t];
    sc[t] = v; __syncthreads();
    int x = v;
    for (int o = 1; o < 256; o <<= 1) {
        int y = (t >= o) ? sc[t - o] : 0;
        __syncthreads();
        x += y;
        sc[t] = x;
        __syncthreads();
    }
    int pref = x - v;
    int g = (b << 8) + t;
    if (g < N) rp[g] = base + pref;
    sc[t] = pref;
    lcnt[t] = 0;
    __syncthreads();
    for (int j = base + t; j < end; j += 256) {
        unsigned w = binned[j];
        int v2 = (int)(w >> 24);
        int s = (int)(w & 0xFFFFFFu);
        int p = atomicAdd(&lcnt[v2], 1);
        csr[base + sc[v2] + p] = s;
    }
}

// ---------------- W1 split: fp32 [128][64] -> bf16-hi/lo transposed [64][128] ----------------

__global__ __launch_bounds__(256) void k_wsplit(const float* __restrict__ W,
                                                unsigned short* __restrict__ WhiT,
                                                unsigned short* __restrict__ WloT) {
    int i = blockIdx.x * 256 + threadIdx.x;
    if (i >= F_IN * F_H) return;
    int k = i >> 6, c = i & 63;                    // W[k][c], C = F_H = 64
    float w = W[i];
    unsigned u = __float_as_uint(w);
    unsigned hi = u & 0xFFFF0000u;                 // truncation split: residual
    float d = w - __uint_as_float(hi);             // captured exactly by lo
    WhiT[c * F_IN + k] = (unsigned short)(hi >> 16);
    WloT[c * F_IN + k] = (unsigned short)(__float_as_uint(d) >> 16);
}

// ---------------- GEMM1 (MFMA): h1 = f16(x @ W1), fused fp32 alphas ----------------

__global__ __launch_bounds__(256) void k_gemm1m(const float* __restrict__ x,
                                                const unsigned short* __restrict__ WhiT,
                                                const unsigned short* __restrict__ WloT,
                                                const float* __restrict__ avs,
                                                const float* __restrict__ avd,
                                                unsigned short* __restrict__ h,
                                                float* __restrict__ as,
                                                float* __restrict__ ad, int N) {
    __shared__ __align__(16) float xs[64][132];    // 33.8 KB; aliased as hs below
    unsigned short (*hs)[72] = (unsigned short(*)[72])xs;
    const int t = threadIdx.x;
    const int wv = t >> 6;
    const int lane = t & 63;
    const int lrow = lane & 15;
    const int lk8 = lane >> 4;
    const int r0 = blockIdx.x * 64;

    // coalesced stage: 64 rows x 32 float4 = 2048 float4, 8 per thread
    {
        const float4* xg = (const float4*)x;
#pragma unroll
        for (int it = 0; it < 8; ++it) {
            int flat = it * 256 + t;               // 0..2047
            int row = flat >> 5, c4 = flat & 31;
            int grow = min(r0 + row, N - 1);
            float4 v = xg[(size_t)grow * 32 + c4];
            *(float4*)&xs[row][c4 * 4] = v;
        }
    }
    __syncthreads();

    // frag load from LDS + split to bf16 hi/lo
    s16x8 ah[4], al[4];
#pragma unroll
    for (int kt = 0; kt < 4; ++kt) {
        const float* rp_ = &xs[wv * 16 + lrow][kt * 32 + lk8 * 8];
        float4 a = *(const float4*)rp_;
        float4 b = *(const float4*)(rp_ + 4);
        float e0[8] = {a.x, a.y, a.z, a.w, b.x, b.y, b.z, b.w};
        unsigned uh[4], ul[4];
#pragma unroll
        for (int p = 0; p < 4; ++p) {
            float a0 = e0[2 * p], a1 = e0[2 * p + 1];
            unsigned u0 = __float_as_uint(a0), u1 = __float_as_uint(a1);
            float d0 = a0 - __uint_as_float(u0 & 0xFFFF0000u);
            float d1 = a1 - __uint_as_float(u1 & 0xFFFF0000u);
            uh[p] = __builtin_amdgcn_perm(u1, u0, 0x07060302u);
            ul[p] = __builtin_amdgcn_perm(__float_as_uint(d1), __float_as_uint(d0), 0x07060302u);
        }
        ah[kt] = __builtin_bit_cast(s16x8, make_uint4(uh[0], uh[1], uh[2], uh[3]));
        al[kt] = __builtin_bit_cast(s16x8, make_uint4(ul[0], ul[1], ul[2], ul[3]));
    }
    __syncthreads();                               // xs reads done -> reuse as hs

    f32x4 acc[4] = {};                             // one 16x16 C-tile per ct
#pragma unroll
    for (int kt = 0; kt < 4; ++kt) {
#pragma unroll
        for (int ct = 0; ct < 4; ++ct) {
            const int boff = (ct * 16 + lrow) * F_IN + kt * 32 + lk8 * 8;
            s16x8 bh = *(const s16x8*)&WhiT[boff];
            s16x8 bl = *(const s16x8*)&WloT[boff];
            acc[ct] = __builtin_amdgcn_mfma_f32_16x16x32_bf16(ah[kt], bh, acc[ct], 0, 0, 0);
            acc[ct] = __builtin_amdgcn_mfma_f32_16x16x32_bf16(al[kt], bh, acc[ct], 0, 0, 0);
            acc[ct] = __builtin_amdgcn_mfma_f32_16x16x32_bf16(ah[kt], bl, acc[ct], 0, 0, 0);
        }
    }

    // fused alphas from fp32 accumulators: reduce over 16 cols (lrow groups)
    float avs_c[4], avd_c[4];
#pragma unroll
    for (int ct = 0; ct < 4; ++ct) {
        avs_c[ct] = avs[ct * 16 + lrow];
        avd_c[ct] = avd[ct * 16 + lrow];
    }
#pragma unroll
    for (int r = 0; r < 4; ++r) {
        float ps = acc[0][r] * avs_c[0] + acc[1][r] * avs_c[1]
                 + acc[2][r] * avs_c[2] + acc[3][r] * avs_c[3];
        float pd = acc[0][r] * avd_c[0] + acc[1][r] * avd_c[1]
                 + acc[2][r] * avd_c[2] + acc[3][r] * avd_c[3];
#pragma unroll
        for (int o = 8; o; o >>= 1) {
            ps += __shfl_xor(ps, o, 16);
            pd += __shfl_xor(pd, o, 16);
        }
        int orow = r0 + wv * 16 + lk8 * 4 + r;
        if (lrow == 0 && orow < N) { as[orow] = ps; ad[orow] = pd; }
    }

    // C -> LDS (f16) -> coalesced global store (NT: consumed later from L3)
#pragma unroll
    for (int ct = 0; ct < 4; ++ct)
#pragma unroll
        for (int r = 0; r < 4; ++r)
            hs[wv * 16 + lk8 * 4 + r][ct * 16 + lrow] = f2h(acc[ct][r]);
    __syncthreads();
    const int row = t >> 2, ch = t & 3;
    const int grow = r0 + row;
    if (grow < N) {
        uint4 v0 = *(const uint4*)&hs[row][ch * 16];
        uint4 v1 = *(const uint4*)&hs[row][ch * 16 + 8];
        uint4* gp = (uint4*)(h + (size_t)grow * F_H + ch * 16);
        nt_store4(gp, v0);
        nt_store4(gp + 1, v1);
    }
}

// ---------------- GEMM2: h2 = f16(out1_f16 @ W2) padded to 64 cols ----------------

__global__ __launch_bounds__(256) void k_gemm2(const unsigned short* __restrict__ xin,
                                               const float* __restrict__ W,
                                               const float* __restrict__ avs,
                                               const float* __restrict__ avd,
                                               unsigned short* __restrict__ h,
                                               float* __restrict__ as,
                                               float* __restrict__ ad, int N) {
    __shared__ __align__(16) float Ws[F_H * F_O];
    for (int i = threadIdx.x; i < F_H * F_O; i += 256) Ws[i] = W[i];
    __syncthreads();
    int t = threadIdx.x;
    int r0 = blockIdx.x * 64 + (t >> 3) * 2;
    int l = t & 7;
    if (r0 >= N) return;
    const uint2* xa = (const uint2*)(xin + (size_t)r0 * F_H);
    const uint2* xb = (const uint2*)(xin + (size_t)(r0 + 1) * F_H);
    float acca[5] = {}, accb[5] = {};
#pragma unroll
    for (int k4 = 0; k4 < F_H / 4; ++k4) {
        uint2 ua = xa[k4];
        uint2 ub = xb[k4];
        h2 a01 = u2h(ua.x), a23 = u2h(ua.y);
        h2 b01 = u2h(ub.x), b23 = u2h(ub.y);
        float xva[4] = {(float)a01.x, (float)a01.y, (float)a23.x, (float)a23.y};
        float xvb[4] = {(float)b01.x, (float)b01.y, (float)b23.x, (float)b23.y};
        int kb = k4 * 4;
#pragma unroll
        for (int kk = 0; kk < 4; ++kk) {
            const float* wr = &Ws[(kb + kk) * F_O + l];
            float w0 = wr[0], w1 = wr[8], w2 = wr[16], w3 = wr[24], w4 = wr[32];
            float xs = xva[kk];
            acca[0] += xs * w0; acca[1] += xs * w1; acca[2] += xs * w2;
            acca[3] += xs * w3; acca[4] += xs * w4;
            float ys = xvb[kk];
            accb[0] += ys * w0; accb[1] += ys * w1; accb[2] += ys * w2;
            accb[3] += ys * w3; accb[4] += ys * w4;
        }
    }
    float psa = 0.f, pda = 0.f, psb = 0.f, pdb = 0.f;
    unsigned short* ra = h + (size_t)r0 * F_H;     // padded row stride 64
    unsigned short* rb = h + (size_t)(r0 + 1) * F_H;
#pragma unroll
    for (int cc = 0; cc < 5; ++cc) {
        int c = l + 8 * cc;
        ra[c] = f2h(acca[cc]);
        rb[c] = f2h(accb[cc]);
        float vs = avs[c], vd = avd[c];
        psa += acca[cc] * vs; pda += acca[cc] * vd;
        psb += accb[cc] * vs; pdb += accb[cc] * vd;
    }
#pragma unroll
    for (int pp = 0; pp < 3; ++pp) {               // zero pad cols 40..63
        int c = 40 + l * 3 + pp;
        ra[c] = 0; rb[c] = 0;
    }
#pragma unroll
    for (int o = 4; o; o >>= 1) {
        psa += __shfl_xor(psa, o, 8);
        pda += __shfl_xor(pda, o, 8);
        psb += __shfl_xor(psb, o, 8);
        pdb += __shfl_xor(pdb, o, 8);
    }
    if (l == 0) { as[r0] = psa; ad[r0] = pda; as[r0 + 1] = psb; ad[r0 + 1] = pdb; }
}

// ---------------- Aggregation: 8 lanes per dst node, 8 nodes per wave ----------------
// Octet loop: edge list padded to x8 (w=0, src=self), 8 gathers in flight,
// 128B-aligned h rows (1 L2 line per edge). NT csr loads + NT output stores
// keep the L2 free for the gather working set.

template <int FOUT, bool RELU, bool LOGSM, bool F16OUT>
__global__ __launch_bounds__(256) void k_agg(const int* __restrict__ rp,
                                             const int* __restrict__ csr,
                                             const float* __restrict__ as,
                                             const float* __restrict__ ad,
                                             const uint4* __restrict__ h4,
                                             const float* __restrict__ bias,
                                             void* __restrict__ outv, int N) {
    constexpr int CAP = 64;                        // LDS-resident edges per node
    __shared__ __align__(16) uint2 wsb[4][8][CAP + 2];
    const int w = threadIdx.x >> 6;
    const int g = (threadIdx.x >> 3) & 7;
    const int c = threadIdx.x & 7;
    const int i = blockIdx.x * 32 + (threadIdx.x >> 3);
    if (i >= N) return;
    const int start = rp[i], end = rp[i + 1];
    const int deg = end - start;
    const int dm = min(deg, CAP);
    const int dmR8 = (dm + 7) & ~7;                // padded to x8 (<= CAP)
    const float adi = ad[i];

    // Phase A: compute edge weights into this group's LDS segment
    for (int idx = c; idx < dm; idx += 8) {
        int srcn = __builtin_nontemporal_load(&csr[start + idx]);
        float e = as[srcn] + adi;
        e = fmaxf(e, 0.2f * e);                    // leaky_relu
        wsb[w][g][idx] = make_uint2(__float_as_uint(__expf(e)), (unsigned)srcn);
    }
    {   // pad (at most 7 entries): w=0, src=self
        int idx = dm + c;
        if (idx < dmR8) wsb[w][g][idx] = make_uint2(0u, (unsigned)i);
    }

    // Phase B: octet loop (same-wave LDS, no barrier needed)
    const uint4* pw = (const uint4*)wsb[w][g];
    float acc[8] = {}, acc2[8] = {};
    float sacc = 0.f;
    const int noct = dmR8 >> 3;
    for (int q = 0; q < noct; ++q) {
        uint4 m0 = pw[4 * q];                      // (w0,s0,w1,s1)
        uint4 m1 = pw[4 * q + 1];                  // (w2,s2,w3,s3)
        uint4 m2 = pw[4 * q + 2];                  // (w4,s4,w5,s5)
        uint4 m3 = pw[4 * q + 3];                  // (w6,s6,w7,s7)
        uint4 hv0 = h4[((size_t)m0.y << 3) + c];
        uint4 hv1 = h4[((size_t)m0.w << 3) + c];
        uint4 hv2 = h4[((size_t)m1.y << 3) + c];
        uint4 hv3 = h4[((size_t)m1.w << 3) + c];
        uint4 hv4 = h4[((size_t)m2.y << 3) + c];
        uint4 hv5 = h4[((size_t)m2.w << 3) + c];
        uint4 hv6 = h4[((size_t)m3.y << 3) + c];
        uint4 hv7 = h4[((size_t)m3.w << 3) + c];
        float w0 = __uint_as_float(m0.x), w1 = __uint_as_float(m0.z);
        float w2 = __uint_as_float(m1.x), w3 = __uint_as_float(m1.z);
        float w4 = __uint_as_float(m2.x), w5 = __uint_as_float(m2.z);
        float w6 = __uint_as_float(m3.x), w7 = __uint_as_float(m3.z);
        sacc += ((w0 + w1) + (w2 + w3)) + ((w4 + w5) + (w6 + w7));
        h2 wp0 = __builtin_amdgcn_cvt_pkrtz(w0, w1);
        h2 wp1 = __builtin_amdgcn_cvt_pkrtz(w2, w3);
        h2 wp2 = __builtin_amdgcn_cvt_pkrtz(w4, w5);
        h2 wp3 = __builtin_amdgcn_cvt_pkrtz(w6, w7);
        acc[0] = fdot2f(wp0, pklo(hv1.x, hv0.x), acc[0]);
        acc[1] = fdot2f(wp0, pkhi(hv1.x, hv0.x), acc[1]);
        acc[2] = fdot2f(wp0, pklo(hv1.y, hv0.y), acc[2]);
        acc[3] = fdot2f(wp0, pkhi(hv1.y, hv0.y), acc[3]);
        acc[4] = fdot2f(wp0, pklo(hv1.z, hv0.z), acc[4]);
        acc[5] = fdot2f(wp0, pkhi(hv1.z, hv0.z), acc[5]);
        acc[6] = fdot2f(wp0, pklo(hv1.w, hv0.w), acc[6]);
        acc[7] = fdot2f(wp0, pkhi(hv1.w, hv0.w), acc[7]);
        acc2[0] = fdot2f(wp1, pklo(hv3.x, hv2.x), acc2[0]);
        acc2[1] = fdot2f(wp1, pkhi(hv3.x, hv2.x), acc2[1]);
        acc2[2] = fdot2f(wp1, pklo(hv3.y, hv2.y), acc2[2]);
        acc2[3] = fdot2f(wp1, pkhi(hv3.y, hv2.y), acc2[3]);
        acc2[4] = fdot2f(wp1, pklo(hv3.z, hv2.z), acc2[4]);
        acc2[5] = fdot2f(wp1, pkhi(hv3.z, hv2.z), acc2[5]);
        acc2[6] = fdot2f(wp1, pklo(hv3.w, hv2.w), acc2[6]);
        acc2[7] = fdot2f(wp1, pkhi(hv3.w, hv2.w), acc2[7]);
        acc[0] = fdot2f(wp2, pklo(hv5.x, hv4.x), acc[0]);
        acc[1] = fdot2f(wp2, pkhi(hv5.x, hv4.x), acc[1]);
        acc[2] = fdot2f(wp2, pklo(hv5.y, hv4.y), acc[2]);
        acc[3] = fdot2f(wp2, pkhi(hv5.y, hv4.y), acc[3]);
        acc[4] = fdot2f(wp2, pklo(hv5.z, hv4.z), acc[4]);
        acc[5] = fdot2f(wp2, pkhi(hv5.z, hv4.z), acc[5]);
        acc[6] = fdot2f(wp2, pklo(hv5.w, hv4.w), acc[6]);
        acc[7] = fdot2f(wp2, pkhi(hv5.w, hv4.w), acc[7]);
        acc2[0] = fdot2f(wp3, pklo(hv7.x, hv6.x), acc2[0]);
        acc2[1] = fdot2f(wp3, pkhi(hv7.x, hv6.x), acc2[1]);
        acc2[2] = fdot2f(wp3, pklo(hv7.y, hv6.y), acc2[2]);
        acc2[3] = fdot2f(wp3, pkhi(hv7.y, hv6.y), acc2[3]);
        acc2[4] = fdot2f(wp3, pklo(hv7.z, hv6.z), acc2[4]);
        acc2[5] = fdot2f(wp3, pkhi(hv7.z, hv6.z), acc2[5]);
        acc2[6] = fdot2f(wp3, pklo(hv7.w, hv6.w), acc2[6]);
        acc2[7] = fdot2f(wp3, pkhi(hv7.w, hv6.w), acc2[7]);
    }

    // rare overflow tail (deg > CAP): single-edge, dup-pair trick with (w,0)
    for (int j = start + dm; j < end; ++j) {
        int srcn = __builtin_nontemporal_load(&csr[j]);
        float e = as[srcn] + adi;
        e = fmaxf(e, 0.2f * e);
        float wv = __expf(e);
        sacc += wv;
        uint4 hv = h4[((size_t)srcn << 3) + c];
        h2 wp = __builtin_amdgcn_cvt_pkrtz(wv, 0.f);
        acc[0] = fdot2f(wp, pklo(hv.x, hv.x), acc[0]);
        acc[1] = fdot2f(wp, pkhi(hv.x, hv.x), acc[1]);
        acc[2] = fdot2f(wp, pklo(hv.y, hv.y), acc[2]);
        acc[3] = fdot2f(wp, pkhi(hv.y, hv.y), acc[3]);
        acc[4] = fdot2f(wp, pklo(hv.z, hv.z), acc[4]);
        acc[5] = fdot2f(wp, pkhi(hv.z, hv.z), acc[5]);
        acc[6] = fdot2f(wp, pklo(hv.w, hv.w), acc[6]);
        acc[7] = fdot2f(wp, pkhi(hv.w, hv.w), acc[7]);
    }

#pragma unroll
    for (int k = 0; k < 8; ++k) acc[k] += acc2[k];
    float inv = 1.f / sacc;                        // identical across the group

    if (!LOGSM) {
        float r[8];
#pragma unroll
        for (int k = 0; k < 8; ++k) {
            r[k] = fmaf(acc[k], inv, bias[8 * c + k]);
            if (RELU) r[k] = fmaxf(r[k], 0.f);
        }
        if (F16OUT) {                              // f16 rows, stride 64 (= F_H)
            unsigned short* oh = (unsigned short*)outv;
            unsigned u0 = (unsigned)f2h(r[0]) | ((unsigned)f2h(r[1]) << 16);
            unsigned u1 = (unsigned)f2h(r[2]) | ((unsigned)f2h(r[3]) << 16);
            unsigned u2 = (unsigned)f2h(r[4]) | ((unsigned)f2h(r[5]) << 16);
            unsigned u3 = (unsigned)f2h(r[6]) | ((unsigned)f2h(r[7]) << 16);
            nt_store4((uint4*)(oh + (size_t)i * F_H + 8 * c),
                      make_uint4(u0, u1, u2, u3));
        } else {
            float* out = (float*)outv;
            float4* op = (float4*)(out + (size_t)i * FOUT + 8 * c);
            nt_storef4(op, make_float4(r[0], r[1], r[2], r[3]));
            nt_storef4(op + 1, make_float4(r[4], r[5], r[6], r[7]));
        }
    } else {
        float* out = (float*)outv;
        constexpr int VC = FOUT / 8;               // valid lane-chunks (5 for FOUT=40)
        bool act = (c < VC);
        float v[8];
#pragma unroll
        for (int k = 0; k < 8; ++k) {
            float bv = bias[act ? 8 * c + k : 0];
            v[k] = act ? fmaf(acc[k], inv, bv) : -INFINITY;
        }
        float mx = v[0];
#pragma unroll
        for (int k = 1; k < 8; ++k) mx = fmaxf(mx, v[k]);
#pragma unroll
        for (int o = 1; o <= 4; o <<= 1) mx = fmaxf(mx, __shfl_xor(mx, o));  // within 8-lane group
        float es = 0.f;
        if (act) {
#pragma unroll
            for (int k = 0; k < 8; ++k) es += __expf(v[k] - mx);
        }
#pragma unroll
        for (int o = 1; o <= 4; o <<= 1) es += __shfl_xor(es, o);
        if (act) {
            float lse = mx + __logf(es);
            float4* op = (float4*)(out + (size_t)i * FOUT + 8 * c);
            nt_storef4(op, make_float4(v[0] - lse, v[1] - lse, v[2] - lse, v[3] - lse));
            nt_storef4(op + 1, make_float4(v[4] - lse, v[5] - lse, v[6] - lse, v[7] - lse));
        }
    }
}

// ---------------- launch ----------------

extern "C" void kernel_launch(void* const* d_in, const int* in_sizes, int n_in,
                              void* d_out, int out_size, void* d_ws, size_t ws_size,
                              hipStream_t stream) {
    const float* x   = (const float*)d_in[0];
    const int* edges = (const int*)d_in[1];
    const float* W1  = (const float*)d_in[2];
    const float* av_s1 = (const float*)d_in[3];
    const float* av_d1 = (const float*)d_in[4];
    const float* b1  = (const float*)d_in[5];
    const float* W2  = (const float*)d_in[6];
    const float* av_s2 = (const float*)d_in[7];
    const float* av_d2 = (const float*)d_in[8];
    const float* b2  = (const float*)d_in[9];
    float* out = (float*)d_out;

    const int N  = in_sizes[0] / F_IN;
    const int E  = in_sizes[1] / 2;
    const int Et = E + N;
    const int NB = (N + 255) >> 8;

    char* p = (char*)d_ws;
    auto alloc = [&](size_t bytes) {
        char* q = p;
        p += (bytes + 255) & ~(size_t)255;
        return (void*)q;
    };
    unsigned short* h1 = (unsigned short*)alloc((size_t)N * F_H * 2);  // f16 [N][64]; reused as h2 (padded to 64)
    unsigned short* out1h = (unsigned short*)alloc((size_t)N * F_H * 2);  // f16 agg1 output [N][64]
    float* as1    = (float*)alloc((size_t)N * 4);
    float* ad1    = (float*)alloc((size_t)N * 4);
    float* as2    = (float*)alloc((size_t)N * 4);
    float* ad2    = (float*)alloc((size_t)N * 4);
    int* rp       = (int*)alloc((size_t)(N + 1) * 4);
    int* bcnt     = (int*)alloc(NBMAX * 4);
    int* bbase    = (int*)alloc(NBMAX * 4);
    int* bcur     = (int*)alloc(NBMAX * 4);
    unsigned* binned = (unsigned*)alloc((size_t)Et * 4);
    int* csr      = (int*)alloc((size_t)Et * 4);
    unsigned short* WhiT = (unsigned short*)alloc((size_t)F_H * F_IN * 2);
    unsigned short* WloT = (unsigned short*)alloc((size_t)F_H * F_IN * 2);
    (void)n_in; (void)out_size; (void)ws_size;

    const int* srcs = edges;
    const int* dsts = edges + E;

    hipMemsetAsync(bcnt, 0, NBMAX * 4, stream);

    k_wsplit<<<(F_IN * F_H + 255) / 256, 256, 0, stream>>>(W1, WhiT, WloT);
    k_binA<<<(Et + 2047) / 2048, 256, 0, stream>>>(dsts, bcnt, E, Et, NB);
    k_binB<<<1, NBMAX, 0, stream>>>(bcnt, bbase, bcur, rp, NB, N, Et);
    k_binC<<<(Et + CHUNK - 1) / CHUNK, 256, 0, stream>>>(srcs, dsts, bcur, binned, E, Et, NB);
    k_binD<<<NB, 256, 0, stream>>>(binned, bbase, bcur, rp, csr, N);

    k_gemm1m<<<(N + 63) / 64, 256, 0, stream>>>(x, WhiT, WloT, av_s1, av_d1, h1, as1, ad1, N);
    int gAgg = (N + 31) / 32;
    k_agg<F_H, true, false, true><<<gAgg, 256, 0, stream>>>(rp, csr, as1, ad1,
                                                            (const uint4*)h1, b1, out1h, N);
    k_gemm2<<<(N + 63) / 64, 256, 0, stream>>>(out1h, W2, av_s2, av_d2, h1, as2, ad2, N);
    k_agg<F_O, false, true, false><<<gAgg, 256, 0, stream>>>(rp, csr, as2, ad2,
                                                             (const uint4*)h1, b2, out, N);
}

// Round 10
// 292.461 us; speedup vs baseline: 1.0042x; 1.0042x over previous
//
#include <hip/hip_runtime.h>
#include <math.h>

// GAT 2-layer, N=100K nodes, E=1.6M edges (+N self loops), fp32 compute,
// f16 feature rows for the edge gather.
// CSR build via 2-level bucket sort (bucket = dst>>8).
//   r9: binD orders each node's edge list by src-CHUNK (src>>14, 2MB table
//   slices): co-resident agg blocks gather from the same L2-fitting slice
//   concurrently -> convert L2 misses (2.5TB/s service ceiling, invariant
//   across ILP/occupancy/layout r2-r8) into L2 hits. agg kernel unchanged.
// agg: 8 lanes per dst node, 8 nodes per wave, octet unroll, f16 pair-dot,
//   128B-aligned [N][64] f16 rows (1 L2 line/edge).
// gemm1 MFMA 3-pass truncation-split bf16.
//   r9: B-frags preloaded to register arrays + launch_bounds(256,2) -- r8
//   showed per-iteration global B loads serialize (~200cy x16/wave, VGPR=56
//   compiler wouldn't hoist); 41us with all pipes idle.
// r10: identical resubmit of r9 -- bench infra failed (container acquire),
//   no kernel verdict was produced.

constexpr int F_IN = 128;
constexpr int F_H  = 64;
constexpr int F_O  = 40;
constexpr int NBMAX = 512;      // max buckets (N <= 131072)
constexpr int CHUNK = 8192;     // edges per block in k_binC
constexpr int NKEY  = 2048;     // 256 nodes x 8 src-chunks (binD)

using h2 = decltype(__builtin_amdgcn_cvt_pkrtz(0.f, 0.f));   // <2 x half>
typedef __attribute__((ext_vector_type(4))) float f32x4;
typedef __attribute__((ext_vector_type(8))) short s16x8;

__device__ __forceinline__ h2 u2h(unsigned u) { return __builtin_bit_cast(h2, u); }

__device__ __forceinline__ float fdot2f(h2 a, h2 b, float c) {
#if __has_builtin(__builtin_amdgcn_fdot2)
    return __builtin_amdgcn_fdot2(a, b, c, false);      // v_dot2_f32_f16
#else
    return c + (float)a.x * (float)b.x + (float)a.y * (float)b.y;
#endif
}
// interleave two u32s of packed f16 pairs: pklo -> (b.lo16, a.lo16), pkhi -> (b.hi16, a.hi16)
__device__ __forceinline__ h2 pklo(unsigned a, unsigned b) {
    return u2h(__builtin_amdgcn_perm(a, b, 0x05040100u));
}
__device__ __forceinline__ h2 pkhi(unsigned a, unsigned b) {
    return u2h(__builtin_amdgcn_perm(a, b, 0x07060302u));
}
__device__ __forceinline__ unsigned short f2h(float f) {   // RNE f32->f16 bits
    _Float16 x = (_Float16)f;
    return __builtin_bit_cast(unsigned short, x);
}
__device__ __forceinline__ void nt_storef4(float4* p, float4 v) {
    __builtin_nontemporal_store(v.x, &p->x);
    __builtin_nontemporal_store(v.y, &p->y);
    __builtin_nontemporal_store(v.z, &p->z);
    __builtin_nontemporal_store(v.w, &p->w);
}

// ---------------- CSR build: bucket sort ----------------

__global__ __launch_bounds__(256) void k_binA(const int* __restrict__ dsts,
                                              int* __restrict__ bcnt,
                                              int E, int Et, int NB) {
    __shared__ int hist[NBMAX];
    for (int i = threadIdx.x; i < NB; i += 256) hist[i] = 0;
    __syncthreads();
    int e0 = blockIdx.x * 2048;
#pragma unroll
    for (int it = 0; it < 8; ++it) {
        int e = e0 + it * 256 + threadIdx.x;
        if (e < Et) {
            int d = (e < E) ? dsts[e] : (e - E);
            atomicAdd(&hist[d >> 8], 1);
        }
    }
    __syncthreads();
    for (int i = threadIdx.x; i < NB; i += 256) {
        int c = hist[i];
        if (c) atomicAdd(&bcnt[i], c);
    }
}

__global__ __launch_bounds__(NBMAX) void k_binB(const int* __restrict__ bcnt,
                                                int* __restrict__ bbase,
                                                int* __restrict__ bcur,
                                                int* __restrict__ rp,
                                                int NB, int N, int Et) {
    __shared__ int sc[NBMAX];
    int t = threadIdx.x;
    int v = (t < NB) ? bcnt[t] : 0;
    sc[t] = v; __syncthreads();
    int x = v;
    for (int o = 1; o < NBMAX; o <<= 1) {
        int y = (t >= o) ? sc[t - o] : 0;
        __syncthreads();
        x += y;
        sc[t] = x;
        __syncthreads();
    }
    if (t < NB) { int b = x - v; bbase[t] = b; bcur[t] = b; }
    if (t == 0) rp[N] = Et;
}

__global__ __launch_bounds__(256) void k_binC(const int* __restrict__ srcs,
                                              const int* __restrict__ dsts,
                                              int* __restrict__ bcur,
                                              unsigned* __restrict__ binned,
                                              int E, int Et, int NB) {
    __shared__ int hist[NBMAX];
    __shared__ int gbase[NBMAX];
    __shared__ int lcnt[NBMAX];
    int t = threadIdx.x;
    for (int i = t; i < NB; i += 256) hist[i] = 0;
    __syncthreads();
    int e0 = blockIdx.x * CHUNK;
#pragma unroll 4
    for (int it = 0; it < CHUNK / 256; ++it) {
        int e = e0 + it * 256 + t;
        if (e < Et) {
            int d = (e < E) ? dsts[e] : (e - E);
            atomicAdd(&hist[d >> 8], 1);
        }
    }
    __syncthreads();
    for (int i = t; i < NB; i += 256) {
        int c = hist[i];
        gbase[i] = c ? atomicAdd(&bcur[i], c) : 0;
        lcnt[i] = 0;
    }
    __syncthreads();
#pragma unroll 4
    for (int it = 0; it < CHUNK / 256; ++it) {
        int e = e0 + it * 256 + t;
        if (e < Et) {
            int s, d;
            if (e < E) { s = srcs[e]; d = dsts[e]; } else { s = e - E; d = s; }
            int b = d >> 8;
            int p = atomicAdd(&lcnt[b], 1);
            binned[gbase[b] + p] = (unsigned)s | ((unsigned)(d & 255) << 24);
        }
    }
}

// binD r9: within each 256-node bucket, order by key = (dst&255)*8 | src>>14.
// Node starts (rp) = prefix at chunk 0; each node's list is src-chunk-ascending
// -> agg blocks sweep the h-table slice-by-slice (cross-block L2 locality).

__global__ __launch_bounds__(256) void k_binD(const unsigned* __restrict__ binned,
                                              const int* __restrict__ bbase,
                                              const int* __restrict__ bcur,
                                              int* __restrict__ rp,
                                              int* __restrict__ csr, int N) {
    __shared__ int hist[NKEY];
    __shared__ int sc2[NKEY];
    __shared__ int lcnt[NKEY];
    __shared__ int tsum[256];
    int b = blockIdx.x, t = threadIdx.x;
    int base = bbase[b], end = bcur[b];
    for (int k = t; k < NKEY; k += 256) { hist[k] = 0; lcnt[k] = 0; }
    __syncthreads();
    for (int j = base + t; j < end; j += 256) {
        unsigned w = binned[j];
        int key = ((int)(w >> 24) << 3) | (int)((w & 0xFFFFFFu) >> 14);
        atomicAdd(&hist[key], 1);
    }
    __syncthreads();
    int myk = t << 3;
    int s = 0;
#pragma unroll
    for (int k = 0; k < 8; ++k) s += hist[myk + k];
    tsum[t] = s; __syncthreads();
    int x = s;
    for (int o = 1; o < 256; o <<= 1) {
        int y = (t >= o) ? tsum[t - o] : 0;
        __syncthreads();
        x += y;
        tsum[t] = x;
        __syncthreads();
    }
    int run = x - s;                               // exclusive prefix (thread = node)
    int g = (b << 8) + t;
    if (g < N) rp[g] = base + run;
#pragma unroll
    for (int k = 0; k < 8; ++k) { sc2[myk + k] = run; run += hist[myk + k]; }
    __syncthreads();
    for (int j = base + t; j < end; j += 256) {
        unsigned w = binned[j];
        int src = (int)(w & 0xFFFFFFu);
        int key = ((int)(w >> 24) << 3) | (src >> 14);
        int p = atomicAdd(&lcnt[key], 1);
        csr[base + sc2[key] + p] = src;
    }
}

// ---------------- W1 split: fp32 [128][64] -> bf16-hi/lo transposed [64][128] ----------------

__global__ __launch_bounds__(256) void k_wsplit(const float* __restrict__ W,
                                                unsigned short* __restrict__ WhiT,
                                                unsigned short* __restrict__ WloT) {
    int i = blockIdx.x * 256 + threadIdx.x;
    if (i >= F_IN * F_H) return;
    int k = i >> 6, c = i & 63;                    // W[k][c], C = F_H = 64
    float w = W[i];
    unsigned u = __float_as_uint(w);
    unsigned hi = u & 0xFFFF0000u;                 // truncation split: residual
    float d = w - __uint_as_float(hi);             // captured exactly by lo
    WhiT[c * F_IN + k] = (unsigned short)(hi >> 16);
    WloT[c * F_IN + k] = (unsigned short)(__float_as_uint(d) >> 16);
}

// ---------------- GEMM1 (MFMA): h1 = f16(x @ W1), fused fp32 alphas ----------------
// r9: all 32 B-frag loads issued into register arrays BEFORE the MFMA chain
// (launch_bounds(256,2) raises the VGPR cap so the compiler can keep them).

__global__ __launch_bounds__(256, 2) void k_gemm1m(const float* __restrict__ x,
                                                   const unsigned short* __restrict__ WhiT,
                                                   const unsigned short* __restrict__ WloT,
                                                   const float* __restrict__ avs,
                                                   const float* __restrict__ avd,
                                                   unsigned short* __restrict__ h,
                                                   float* __restrict__ as,
                                                   float* __restrict__ ad, int N) {
    __shared__ __align__(16) float xs[64][132];    // 33.8 KB; aliased as hs below
    unsigned short (*hs)[72] = (unsigned short(*)[72])xs;
    const int t = threadIdx.x;
    const int wv = t >> 6;
    const int lane = t & 63;
    const int lrow = lane & 15;
    const int lk8 = lane >> 4;
    const int r0 = blockIdx.x * 64;

    // coalesced stage: 64 rows x 32 float4 = 2048 float4, 8 per thread
    {
        const float4* xg = (const float4*)x;
#pragma unroll
        for (int it = 0; it < 8; ++it) {
            int flat = it * 256 + t;               // 0..2047
            int row = flat >> 5, c4 = flat & 31;
            int grow = min(r0 + row, N - 1);
            float4 v = xg[(size_t)grow * 32 + c4];
            *(float4*)&xs[row][c4 * 4] = v;
        }
    }

    // preload ALL B-frags (block-invariant tables, L2-hot) while x stages
    s16x8 bh[4][4], bl[4][4];
#pragma unroll
    for (int kt = 0; kt < 4; ++kt)
#pragma unroll
        for (int ct = 0; ct < 4; ++ct) {
            const int boff = (ct * 16 + lrow) * F_IN + kt * 32 + lk8 * 8;
            bh[kt][ct] = *(const s16x8*)&WhiT[boff];
            bl[kt][ct] = *(const s16x8*)&WloT[boff];
        }
    __syncthreads();

    // frag load from LDS + split to bf16 hi/lo
    s16x8 ah[4], al[4];
#pragma unroll
    for (int kt = 0; kt < 4; ++kt) {
        const float* rp_ = &xs[wv * 16 + lrow][kt * 32 + lk8 * 8];
        float4 a = *(const float4*)rp_;
        float4 b = *(const float4*)(rp_ + 4);
        float e0[8] = {a.x, a.y, a.z, a.w, b.x, b.y, b.z, b.w};
        unsigned uh[4], ul[4];
#pragma unroll
        for (int p = 0; p < 4; ++p) {
            float a0 = e0[2 * p], a1 = e0[2 * p + 1];
            unsigned u0 = __float_as_uint(a0), u1 = __float_as_uint(a1);
            float d0 = a0 - __uint_as_float(u0 & 0xFFFF0000u);
            float d1 = a1 - __uint_as_float(u1 & 0xFFFF0000u);
            uh[p] = __builtin_amdgcn_perm(u1, u0, 0x07060302u);
            ul[p] = __builtin_amdgcn_perm(__float_as_uint(d1), __float_as_uint(d0), 0x07060302u);
        }
        ah[kt] = __builtin_bit_cast(s16x8, make_uint4(uh[0], uh[1], uh[2], uh[3]));
        al[kt] = __builtin_bit_cast(s16x8, make_uint4(ul[0], ul[1], ul[2], ul[3]));
    }
    __syncthreads();                               // xs reads done -> reuse as hs

    f32x4 acc[4] = {};                             // one 16x16 C-tile per ct
#pragma unroll
    for (int kt = 0; kt < 4; ++kt) {
#pragma unroll
        for (int ct = 0; ct < 4; ++ct) {
            acc[ct] = __builtin_amdgcn_mfma_f32_16x16x32_bf16(ah[kt], bh[kt][ct], acc[ct], 0, 0, 0);
            acc[ct] = __builtin_amdgcn_mfma_f32_16x16x32_bf16(al[kt], bh[kt][ct], acc[ct], 0, 0, 0);
            acc[ct] = __builtin_amdgcn_mfma_f32_16x16x32_bf16(ah[kt], bl[kt][ct], acc[ct], 0, 0, 0);
        }
    }

    // fused alphas from fp32 accumulators: reduce over 16 cols (lrow groups)
    float avs_c[4], avd_c[4];
#pragma unroll
    for (int ct = 0; ct < 4; ++ct) {
        avs_c[ct] = avs[ct * 16 + lrow];
        avd_c[ct] = avd[ct * 16 + lrow];
    }
#pragma unroll
    for (int r = 0; r < 4; ++r) {
        float ps = acc[0][r] * avs_c[0] + acc[1][r] * avs_c[1]
                 + acc[2][r] * avs_c[2] + acc[3][r] * avs_c[3];
        float pd = acc[0][r] * avd_c[0] + acc[1][r] * avd_c[1]
                 + acc[2][r] * avd_c[2] + acc[3][r] * avd_c[3];
#pragma unroll
        for (int o = 8; o; o >>= 1) {
            ps += __shfl_xor(ps, o, 16);
            pd += __shfl_xor(pd, o, 16);
        }
        int orow = r0 + wv * 16 + lk8 * 4 + r;
        if (lrow == 0 && orow < N) { as[orow] = ps; ad[orow] = pd; }
    }

    // C -> LDS (f16) -> coalesced global store (normal: seed L2/L3 for agg)
#pragma unroll
    for (int ct = 0; ct < 4; ++ct)
#pragma unroll
        for (int r = 0; r < 4; ++r)
            hs[wv * 16 + lk8 * 4 + r][ct * 16 + lrow] = f2h(acc[ct][r]);
    __syncthreads();
    const int row = t >> 2, ch = t & 3;
    const int grow = r0 + row;
    if (grow < N) {
        uint4 v0 = *(const uint4*)&hs[row][ch * 16];
        uint4 v1 = *(const uint4*)&hs[row][ch * 16 + 8];
        uint4* gp = (uint4*)(h + (size_t)grow * F_H + ch * 16);
        gp[0] = v0; gp[1] = v1;
    }
}

// ---------------- GEMM2: h2 = f16(out1_f16 @ W2) padded to 64 cols ----------------

__global__ __launch_bounds__(256) void k_gemm2(const unsigned short* __restrict__ xin,
                                               const float* __restrict__ W,
                                               const float* __restrict__ avs,
                                               const float* __restrict__ avd,
                                               unsigned short* __restrict__ h,
                                               float* __restrict__ as,
                                               float* __restrict__ ad, int N) {
    __shared__ __align__(16) float Ws[F_H * F_O];
    for (int i = threadIdx.x; i < F_H * F_O; i += 256) Ws[i] = W[i];
    __syncthreads();
    int t = threadIdx.x;
    int r0 = blockIdx.x * 64 + (t >> 3) * 2;
    int l = t & 7;
    if (r0 >= N) return;
    const uint2* xa = (const uint2*)(xin + (size_t)r0 * F_H);
    const uint2* xb = (const uint2*)(xin + (size_t)(r0 + 1) * F_H);
    float acca[5] = {}, accb[5] = {};
#pragma unroll
    for (int k4 = 0; k4 < F_H / 4; ++k4) {
        uint2 ua = xa[k4];
        uint2 ub = xb[k4];
        h2 a01 = u2h(ua.x), a23 = u2h(ua.y);
        h2 b01 = u2h(ub.x), b23 = u2h(ub.y);
        float xva[4] = {(float)a01.x, (float)a01.y, (float)a23.x, (float)a23.y};
        float xvb[4] = {(float)b01.x, (float)b01.y, (float)b23.x, (float)b23.y};
        int kb = k4 * 4;
#pragma unroll
        for (int kk = 0; kk < 4; ++kk) {
            const float* wr = &Ws[(kb + kk) * F_O + l];
            float w0 = wr[0], w1 = wr[8], w2 = wr[16], w3 = wr[24], w4 = wr[32];
            float xs = xva[kk];
            acca[0] += xs * w0; acca[1] += xs * w1; acca[2] += xs * w2;
            acca[3] += xs * w3; acca[4] += xs * w4;
            float ys = xvb[kk];
            accb[0] += ys * w0; accb[1] += ys * w1; accb[2] += ys * w2;
            accb[3] += ys * w3; accb[4] += ys * w4;
        }
    }
    float psa = 0.f, pda = 0.f, psb = 0.f, pdb = 0.f;
    unsigned short* ra = h + (size_t)r0 * F_H;     // padded row stride 64
    unsigned short* rb = h + (size_t)(r0 + 1) * F_H;
#pragma unroll
    for (int cc = 0; cc < 5; ++cc) {
        int c = l + 8 * cc;
        ra[c] = f2h(acca[cc]);
        rb[c] = f2h(accb[cc]);
        float vs = avs[c], vd = avd[c];
        psa += acca[cc] * vs; pda += acca[cc] * vd;
        psb += accb[cc] * vs; pdb += accb[cc] * vd;
    }
#pragma unroll
    for (int pp = 0; pp < 3; ++pp) {               // zero pad cols 40..63
        int c = 40 + l * 3 + pp;
        ra[c] = 0; rb[c] = 0;
    }
#pragma unroll
    for (int o = 4; o; o >>= 1) {
        psa += __shfl_xor(psa, o, 8);
        pda += __shfl_xor(pda, o, 8);
        psb += __shfl_xor(psb, o, 8);
        pdb += __shfl_xor(pdb, o, 8);
    }
    if (l == 0) { as[r0] = psa; ad[r0] = pda; as[r0 + 1] = psb; ad[r0 + 1] = pdb; }
}

// ---------------- Aggregation: 8 lanes per dst node, 8 nodes per wave ----------------
// Octet loop: edge list padded to x8 (w=0, src=self), 8 gathers in flight,
// 128B-aligned h rows. Edge lists arrive src-chunk-ordered from binD.

template <int FOUT, bool RELU, bool LOGSM, bool F16OUT>
__global__ __launch_bounds__(256) void k_agg(const int* __restrict__ rp,
                                             const int* __restrict__ csr,
                                             const float* __restrict__ as,
                                             const float* __restrict__ ad,
                                             const uint4* __restrict__ h4,
                                             const float* __restrict__ bias,
                                             void* __restrict__ outv, int N) {
    constexpr int CAP = 64;                        // LDS-resident edges per node
    __shared__ __align__(16) uint2 wsb[4][8][CAP + 2];
    const int w = threadIdx.x >> 6;
    const int g = (threadIdx.x >> 3) & 7;
    const int c = threadIdx.x & 7;
    const int i = blockIdx.x * 32 + (threadIdx.x >> 3);
    if (i >= N) return;
    const int start = rp[i], end = rp[i + 1];
    const int deg = end - start;
    const int dm = min(deg, CAP);
    const int dmR8 = (dm + 7) & ~7;                // padded to x8 (<= CAP)
    const float adi = ad[i];

    // Phase A: compute edge weights into this group's LDS segment
    for (int idx = c; idx < dm; idx += 8) {
        int srcn = __builtin_nontemporal_load(&csr[start + idx]);
        float e = as[srcn] + adi;
        e = fmaxf(e, 0.2f * e);                    // leaky_relu
        wsb[w][g][idx] = make_uint2(__float_as_uint(__expf(e)), (unsigned)srcn);
    }
    {   // pad (at most 7 entries): w=0, src=self
        int idx = dm + c;
        if (idx < dmR8) wsb[w][g][idx] = make_uint2(0u, (unsigned)i);
    }

    // Phase B: octet loop (same-wave LDS, no barrier needed)
    const uint4* pw = (const uint4*)wsb[w][g];
    float acc[8] = {}, acc2[8] = {};
    float sacc = 0.f;
    const int noct = dmR8 >> 3;
    for (int q = 0; q < noct; ++q) {
        uint4 m0 = pw[4 * q];                      // (w0,s0,w1,s1)
        uint4 m1 = pw[4 * q + 1];                  // (w2,s2,w3,s3)
        uint4 m2 = pw[4 * q + 2];                  // (w4,s4,w5,s5)
        uint4 m3 = pw[4 * q + 3];                  // (w6,s6,w7,s7)
        uint4 hv0 = h4[((size_t)m0.y << 3) + c];
        uint4 hv1 = h4[((size_t)m0.w << 3) + c];
        uint4 hv2 = h4[((size_t)m1.y << 3) + c];
        uint4 hv3 = h4[((size_t)m1.w << 3) + c];
        uint4 hv4 = h4[((size_t)m2.y << 3) + c];
        uint4 hv5 = h4[((size_t)m2.w << 3) + c];
        uint4 hv6 = h4[((size_t)m3.y << 3) + c];
        uint4 hv7 = h4[((size_t)m3.w << 3) + c];
        float w0 = __uint_as_float(m0.x), w1 = __uint_as_float(m0.z);
        float w2 = __uint_as_float(m1.x), w3 = __uint_as_float(m1.z);
        float w4 = __uint_as_float(m2.x), w5 = __uint_as_float(m2.z);
        float w6 = __uint_as_float(m3.x), w7 = __uint_as_float(m3.z);
        sacc += ((w0 + w1) + (w2 + w3)) + ((w4 + w5) + (w6 + w7));
        h2 wp0 = __builtin_amdgcn_cvt_pkrtz(w0, w1);
        h2 wp1 = __builtin_amdgcn_cvt_pkrtz(w2, w3);
        h2 wp2 = __builtin_amdgcn_cvt_pkrtz(w4, w5);
        h2 wp3 = __builtin_amdgcn_cvt_pkrtz(w6, w7);
        acc[0] = fdot2f(wp0, pklo(hv1.x, hv0.x), acc[0]);
        acc[1] = fdot2f(wp0, pkhi(hv1.x, hv0.x), acc[1]);
        acc[2] = fdot2f(wp0, pklo(hv1.y, hv0.y), acc[2]);
        acc[3] = fdot2f(wp0, pkhi(hv1.y, hv0.y), acc[3]);
        acc[4] = fdot2f(wp0, pklo(hv1.z, hv0.z), acc[4]);
        acc[5] = fdot2f(wp0, pkhi(hv1.z, hv0.z), acc[5]);
        acc[6] = fdot2f(wp0, pklo(hv1.w, hv0.w), acc[6]);
        acc[7] = fdot2f(wp0, pkhi(hv1.w, hv0.w), acc[7]);
        acc2[0] = fdot2f(wp1, pklo(hv3.x, hv2.x), acc2[0]);
        acc2[1] = fdot2f(wp1, pkhi(hv3.x, hv2.x), acc2[1]);
        acc2[2] = fdot2f(wp1, pklo(hv3.y, hv2.y), acc2[2]);
        acc2[3] = fdot2f(wp1, pkhi(hv3.y, hv2.y), acc2[3]);
        acc2[4] = fdot2f(wp1, pklo(hv3.z, hv2.z), acc2[4]);
        acc2[5] = fdot2f(wp1, pkhi(hv3.z, hv2.z), acc2[5]);
        acc2[6] = fdot2f(wp1, pklo(hv3.w, hv2.w), acc2[6]);
        acc2[7] = fdot2f(wp1, pkhi(hv3.w, hv2.w), acc2[7]);
        acc[0] = fdot2f(wp2, pklo(hv5.x, hv4.x), acc[0]);
        acc[1] = fdot2f(wp2, pkhi(hv5.x, hv4.x), acc[1]);
        acc[2] = fdot2f(wp2, pklo(hv5.y, hv4.y), acc[2]);
        acc[3] = fdot2f(wp2, pkhi(hv5.y, hv4.y), acc[3]);
        acc[4] = fdot2f(wp2, pklo(hv5.z, hv4.z), acc[4]);
        acc[5] = fdot2f(wp2, pkhi(hv5.z, hv4.z), acc[5]);
        acc[6] = fdot2f(wp2, pklo(hv5.w, hv4.w), acc[6]);
        acc[7] = fdot2f(wp2, pkhi(hv5.w, hv4.w), acc[7]);
        acc2[0] = fdot2f(wp3, pklo(hv7.x, hv6.x), acc2[0]);
        acc2[1] = fdot2f(wp3, pkhi(hv7.x, hv6.x), acc2[1]);
        acc2[2] = fdot2f(wp3, pklo(hv7.y, hv6.y), acc2[2]);
        acc2[3] = fdot2f(wp3, pkhi(hv7.y, hv6.y), acc2[3]);
        acc2[4] = fdot2f(wp3, pklo(hv7.z, hv6.z), acc2[4]);
        acc2[5] = fdot2f(wp3, pkhi(hv7.z, hv6.z), acc2[5]);
        acc2[6] = fdot2f(wp3, pklo(hv7.w, hv6.w), acc2[6]);
        acc2[7] = fdot2f(wp3, pkhi(hv7.w, hv6.w), acc2[7]);
    }

    // rare overflow tail (deg > CAP): single-edge, dup-pair trick with (w,0)
    for (int j = start + dm; j < end; ++j) {
        int srcn = __builtin_nontemporal_load(&csr[j]);
        float e = as[srcn] + adi;
        e = fmaxf(e, 0.2f * e);
        float wv = __expf(e);
        sacc += wv;
        uint4 hv = h4[((size_t)srcn << 3) + c];
        h2 wp = __builtin_amdgcn_cvt_pkrtz(wv, 0.f);
        acc[0] = fdot2f(wp, pklo(hv.x, hv.x), acc[0]);
        acc[1] = fdot2f(wp, pkhi(hv.x, hv.x), acc[1]);
        acc[2] = fdot2f(wp, pklo(hv.y, hv.y), acc[2]);
        acc[3] = fdot2f(wp, pkhi(hv.y, hv.y), acc[3]);
        acc[4] = fdot2f(wp, pklo(hv.z, hv.z), acc[4]);
        acc[5] = fdot2f(wp, pkhi(hv.z, hv.z), acc[5]);
        acc[6] = fdot2f(wp, pklo(hv.w, hv.w), acc[6]);
        acc[7] = fdot2f(wp, pkhi(hv.w, hv.w), acc[7]);
    }

#pragma unroll
    for (int k = 0; k < 8; ++k) acc[k] += acc2[k];
    float inv = 1.f / sacc;                        // identical across the group

    if (!LOGSM) {
        float r[8];
#pragma unroll
        for (int k = 0; k < 8; ++k) {
            r[k] = fmaf(acc[k], inv, bias[8 * c + k]);
            if (RELU) r[k] = fmaxf(r[k], 0.f);
        }
        if (F16OUT) {                              // f16 rows, stride 64 (= F_H)
            unsigned short* oh = (unsigned short*)outv;
            unsigned u0 = (unsigned)f2h(r[0]) | ((unsigned)f2h(r[1]) << 16);
            unsigned u1 = (unsigned)f2h(r[2]) | ((unsigned)f2h(r[3]) << 16);
            unsigned u2 = (unsigned)f2h(r[4]) | ((unsigned)f2h(r[5]) << 16);
            unsigned u3 = (unsigned)f2h(r[6]) | ((unsigned)f2h(r[7]) << 16);
            *(uint4*)(oh + (size_t)i * F_H + 8 * c) = make_uint4(u0, u1, u2, u3);
        } else {
            float* out = (float*)outv;
            float4* op = (float4*)(out + (size_t)i * FOUT + 8 * c);
            nt_storef4(op, make_float4(r[0], r[1], r[2], r[3]));
            nt_storef4(op + 1, make_float4(r[4], r[5], r[6], r[7]));
        }
    } else {
        float* out = (float*)outv;
        constexpr int VC = FOUT / 8;               // valid lane-chunks (5 for FOUT=40)
        bool act = (c < VC);
        float v[8];
#pragma unroll
        for (int k = 0; k < 8; ++k) {
            float bv = bias[act ? 8 * c + k : 0];
            v[k] = act ? fmaf(acc[k], inv, bv) : -INFINITY;
        }
        float mx = v[0];
#pragma unroll
        for (int k = 1; k < 8; ++k) mx = fmaxf(mx, v[k]);
#pragma unroll
        for (int o = 1; o <= 4; o <<= 1) mx = fmaxf(mx, __shfl_xor(mx, o));  // within 8-lane group
        float es = 0.f;
        if (act) {
#pragma unroll
            for (int k = 0; k < 8; ++k) es += __expf(v[k] - mx);
        }
#pragma unroll
        for (int o = 1; o <= 4; o <<= 1) es += __shfl_xor(es, o);
        if (act) {
            float lse = mx + __logf(es);
            float4* op = (float4*)(out + (size_t)i * FOUT + 8 * c);
            nt_storef4(op, make_float4(v[0] - lse, v[1] - lse, v[2] - lse, v[3] - lse));
            nt_storef4(op + 1, make_float4(v[4] - lse, v[5] - lse, v[6] - lse, v[7] - lse));
        }
    }
}

// ---------------- launch ----------------

extern "C" void kernel_launch(void* const* d_in, const int* in_sizes, int n_in,
                              void* d_out, int out_size, void* d_ws, size_t ws_size,
                              hipStream_t stream) {
    const float* x   = (const float*)d_in[0];
    const int* edges = (const int*)d_in[1];
    const float* W1  = (const float*)d_in[2];
    const float* av_s1 = (const float*)d_in[3];
    const float* av_d1 = (const float*)d_in[4];
    const float* b1  = (const float*)d_in[5];
    const float* W2  = (const float*)d_in[6];
    const float* av_s2 = (const float*)d_in[7];
    const float* av_d2 = (const float*)d_in[8];
    const float* b2  = (const float*)d_in[9];
    float* out = (float*)d_out;

    const int N  = in_sizes[0] / F_IN;
    const int E  = in_sizes[1] / 2;
    const int Et = E + N;
    const int NB = (N + 255) >> 8;

    char* p = (char*)d_ws;
    auto alloc = [&](size_t bytes) {
        char* q = p;
        p += (bytes + 255) & ~(size_t)255;
        return (void*)q;
    };
    unsigned short* h1 = (unsigned short*)alloc((size_t)N * F_H * 2);  // f16 [N][64]; reused as h2 (padded to 64)
    unsigned short* out1h = (unsigned short*)alloc((size_t)N * F_H * 2);  // f16 agg1 output [N][64]
    float* as1    = (float*)alloc((size_t)N * 4);
    float* ad1    = (float*)alloc((size_t)N * 4);
    float* as2    = (float*)alloc((size_t)N * 4);
    float* ad2    = (float*)alloc((size_t)N * 4);
    int* rp       = (int*)alloc((size_t)(N + 1) * 4);
    int* bcnt     = (int*)alloc(NBMAX * 4);
    int* bbase    = (int*)alloc(NBMAX * 4);
    int* bcur     = (int*)alloc(NBMAX * 4);
    unsigned* binned = (unsigned*)alloc((size_t)Et * 4);
    int* csr      = (int*)alloc((size_t)Et * 4);
    unsigned short* WhiT = (unsigned short*)alloc((size_t)F_H * F_IN * 2);
    unsigned short* WloT = (unsigned short*)alloc((size_t)F_H * F_IN * 2);
    (void)n_in; (void)out_size; (void)ws_size;

    const int* srcs = edges;
    const int* dsts = edges + E;

    hipMemsetAsync(bcnt, 0, NBMAX * 4, stream);

    k_wsplit<<<(F_IN * F_H + 255) / 256, 256, 0, stream>>>(W1, WhiT, WloT);
    k_binA<<<(Et + 2047) / 2048, 256, 0, stream>>>(dsts, bcnt, E, Et, NB);
    k_binB<<<1, NBMAX, 0, stream>>>(bcnt, bbase, bcur, rp, NB, N, Et);
    k_binC<<<(Et + CHUNK - 1) / CHUNK, 256, 0, stream>>>(srcs, dsts, bcur, binned, E, Et, NB);
    k_binD<<<NB, 256, 0, stream>>>(binned, bbase, bcur, rp, csr, N);

    k_gemm1m<<<(N + 63) / 64, 256, 0, stream>>>(x, WhiT, WloT, av_s1, av_d1, h1, as1, ad1, N);
    int gAgg = (N + 31) / 32;
    k_agg<F_H, true, false, true><<<gAgg, 256, 0, stream>>>(rp, csr, as1, ad1,
                                                            (const uint4*)h1, b1, out1h, N);
    k_gemm2<<<(N + 63) / 64, 256, 0, stream>>>(out1h, W2, av_s2, av_d2, h1, as2, ad2, N);
    k_agg<F_O, false, true, false><<<gAgg, 256, 0, stream>>>(rp, csr, as2, ad2,
                                                             (const uint4*)h1, b2, out, N);
}

// Round 11
// 283.120 us; speedup vs baseline: 1.0374x; 1.0330x over previous
//
#include <hip/hip_runtime.h>
#include <math.h>

// GAT 2-layer, N=100K nodes, E=1.6M edges (+N self loops), fp32 compute,
// f16 feature rows for the edge gather.
// CSR build via 2-level bucket sort (bucket = dst>>8); binD orders each
// node's list by src-chunk (neutral-to-slightly-positive, kept).
// agg: 8 lanes per dst node, 8 nodes per wave, octet unroll, f16 pair-dot,
//   128B-aligned [N][64] f16 rows (1 L2 line/edge). Both aggs are at the
//   compulsory cross-XCD random-line floor (~87MB = 12.8MB x ~7 XCDs at
//   ~2.6TB/s; invariant across 8 levers r2-r10).
// r11: GEMM2 ELIMINATED by algebra: out2 = (sum coef*out1)@W2 + b2 (matmul
//   distributes over the weighted sum; sum coef = 1). agg2 gathers out1h
//   directly and applies W2+b2+logsoftmax in its epilogue (LDS W2^T).
//   Attention logits as2/ad2 = out1.(W2 a2) + b2.a2 fused into agg1's
//   epilogue via precomputed 64-vectors (k_wprep).
// gemm1 MFMA 3-pass truncation-split bf16, B-frags preloaded to registers
//   (launch_bounds(256,2)) -- r10 confirmed this removed the 41us stall.

constexpr int F_IN = 128;
constexpr int F_H  = 64;
constexpr int F_O  = 40;
constexpr int NBMAX = 512;      // max buckets (N <= 131072)
constexpr int CHUNK = 8192;     // edges per block in k_binC
constexpr int NKEY  = 2048;     // 256 nodes x 8 src-chunks (binD)

using h2 = decltype(__builtin_amdgcn_cvt_pkrtz(0.f, 0.f));   // <2 x half>
typedef __attribute__((ext_vector_type(4))) float f32x4;
typedef __attribute__((ext_vector_type(8))) short s16x8;

__device__ __forceinline__ h2 u2h(unsigned u) { return __builtin_bit_cast(h2, u); }

__device__ __forceinline__ float fdot2f(h2 a, h2 b, float c) {
#if __has_builtin(__builtin_amdgcn_fdot2)
    return __builtin_amdgcn_fdot2(a, b, c, false);      // v_dot2_f32_f16
#else
    return c + (float)a.x * (float)b.x + (float)a.y * (float)b.y;
#endif
}
// interleave two u32s of packed f16 pairs: pklo -> (b.lo16, a.lo16), pkhi -> (b.hi16, a.hi16)
__device__ __forceinline__ h2 pklo(unsigned a, unsigned b) {
    return u2h(__builtin_amdgcn_perm(a, b, 0x05040100u));
}
__device__ __forceinline__ h2 pkhi(unsigned a, unsigned b) {
    return u2h(__builtin_amdgcn_perm(a, b, 0x07060302u));
}
__device__ __forceinline__ unsigned short f2h(float f) {   // RNE f32->f16 bits
    _Float16 x = (_Float16)f;
    return __builtin_bit_cast(unsigned short, x);
}

// ---------------- CSR build: bucket sort ----------------

__global__ __launch_bounds__(256) void k_binA(const int* __restrict__ dsts,
                                              int* __restrict__ bcnt,
                                              int E, int Et, int NB) {
    __shared__ int hist[NBMAX];
    for (int i = threadIdx.x; i < NB; i += 256) hist[i] = 0;
    __syncthreads();
    int e0 = blockIdx.x * 2048;
#pragma unroll
    for (int it = 0; it < 8; ++it) {
        int e = e0 + it * 256 + threadIdx.x;
        if (e < Et) {
            int d = (e < E) ? dsts[e] : (e - E);
            atomicAdd(&hist[d >> 8], 1);
        }
    }
    __syncthreads();
    for (int i = threadIdx.x; i < NB; i += 256) {
        int c = hist[i];
        if (c) atomicAdd(&bcnt[i], c);
    }
}

__global__ __launch_bounds__(NBMAX) void k_binB(const int* __restrict__ bcnt,
                                                int* __restrict__ bbase,
                                                int* __restrict__ bcur,
                                                int* __restrict__ rp,
                                                int NB, int N, int Et) {
    __shared__ int sc[NBMAX];
    int t = threadIdx.x;
    int v = (t < NB) ? bcnt[t] : 0;
    sc[t] = v; __syncthreads();
    int x = v;
    for (int o = 1; o < NBMAX; o <<= 1) {
        int y = (t >= o) ? sc[t - o] : 0;
        __syncthreads();
        x += y;
        sc[t] = x;
        __syncthreads();
    }
    if (t < NB) { int b = x - v; bbase[t] = b; bcur[t] = b; }
    if (t == 0) rp[N] = Et;
}

__global__ __launch_bounds__(256) void k_binC(const int* __restrict__ srcs,
                                              const int* __restrict__ dsts,
                                              int* __restrict__ bcur,
                                              unsigned* __restrict__ binned,
                                              int E, int Et, int NB) {
    __shared__ int hist[NBMAX];
    __shared__ int gbase[NBMAX];
    __shared__ int lcnt[NBMAX];
    int t = threadIdx.x;
    for (int i = t; i < NB; i += 256) hist[i] = 0;
    __syncthreads();
    int e0 = blockIdx.x * CHUNK;
#pragma unroll 4
    for (int it = 0; it < CHUNK / 256; ++it) {
        int e = e0 + it * 256 + t;
        if (e < Et) {
            int d = (e < E) ? dsts[e] : (e - E);
            atomicAdd(&hist[d >> 8], 1);
        }
    }
    __syncthreads();
    for (int i = t; i < NB; i += 256) {
        int c = hist[i];
        gbase[i] = c ? atomicAdd(&bcur[i], c) : 0;
        lcnt[i] = 0;
    }
    __syncthreads();
#pragma unroll 4
    for (int it = 0; it < CHUNK / 256; ++it) {
        int e = e0 + it * 256 + t;
        if (e < Et) {
            int s, d;
            if (e < E) { s = srcs[e]; d = dsts[e]; } else { s = e - E; d = s; }
            int b = d >> 8;
            int p = atomicAdd(&lcnt[b], 1);
            binned[gbase[b] + p] = (unsigned)s | ((unsigned)(d & 255) << 24);
        }
    }
}

// binD: within each 256-node bucket, order by key = (dst&255)*8 | src>>14.

__global__ __launch_bounds__(256) void k_binD(const unsigned* __restrict__ binned,
                                              const int* __restrict__ bbase,
                                              const int* __restrict__ bcur,
                                              int* __restrict__ rp,
                                              int* __restrict__ csr, int N) {
    __shared__ int hist[NKEY];
    __shared__ int sc2[NKEY];
    __shared__ int lcnt[NKEY];
    __shared__ int tsum[256];
    int b = blockIdx.x, t = threadIdx.x;
    int base = bbase[b], end = bcur[b];
    for (int k = t; k < NKEY; k += 256) { hist[k] = 0; lcnt[k] = 0; }
    __syncthreads();
    for (int j = base + t; j < end; j += 256) {
        unsigned w = binned[j];
        int key = ((int)(w >> 24) << 3) | (int)((w & 0xFFFFFFu) >> 14);
        atomicAdd(&hist[key], 1);
    }
    __syncthreads();
    int myk = t << 3;
    int s = 0;
#pragma unroll
    for (int k = 0; k < 8; ++k) s += hist[myk + k];
    tsum[t] = s; __syncthreads();
    int x = s;
    for (int o = 1; o < 256; o <<= 1) {
        int y = (t >= o) ? tsum[t - o] : 0;
        __syncthreads();
        x += y;
        tsum[t] = x;
        __syncthreads();
    }
    int run = x - s;                               // exclusive prefix (thread = node)
    int g = (b << 8) + t;
    if (g < N) rp[g] = base + run;
#pragma unroll
    for (int k = 0; k < 8; ++k) { sc2[myk + k] = run; run += hist[myk + k]; }
    __syncthreads();
    for (int j = base + t; j < end; j += 256) {
        unsigned w = binned[j];
        int src = (int)(w & 0xFFFFFFu);
        int key = ((int)(w >> 24) << 3) | (src >> 14);
        int p = atomicAdd(&lcnt[key], 1);
        csr[base + sc2[key] + p] = src;
    }
}

// ---------------- W1 split: fp32 [128][64] -> bf16-hi/lo transposed [64][128] ----------------

__global__ __launch_bounds__(256) void k_wsplit(const float* __restrict__ W,
                                                unsigned short* __restrict__ WhiT,
                                                unsigned short* __restrict__ WloT) {
    int i = blockIdx.x * 256 + threadIdx.x;
    if (i >= F_IN * F_H) return;
    int k = i >> 6, c = i & 63;                    // W[k][c], C = F_H = 64
    float w = W[i];
    unsigned u = __float_as_uint(w);
    unsigned hi = u & 0xFFFF0000u;                 // truncation split: residual
    float d = w - __uint_as_float(hi);             // captured exactly by lo
    WhiT[c * F_IN + k] = (unsigned short)(hi >> 16);
    WloT[c * F_IN + k] = (unsigned short)(__float_as_uint(d) >> 16);
}

// ---------------- W2 prep: wasL = W2 @ a_src2, wadL = W2 @ a_dst2, csb = b2.a ----------------

__global__ __launch_bounds__(64) void k_wprep(const float* __restrict__ W2,
                                              const float* __restrict__ a2s,
                                              const float* __restrict__ a2d,
                                              const float* __restrict__ b2,
                                              float* __restrict__ wasL,
                                              float* __restrict__ wadL,
                                              float* __restrict__ csb) {
    int k = threadIdx.x;                           // 0..63
    float s = 0.f, d = 0.f;
    for (int c = 0; c < F_O; ++c) {
        float w = W2[k * F_O + c];
        s += w * a2s[c];
        d += w * a2d[c];
    }
    wasL[k] = s;
    wadL[k] = d;
    if (k == 0) {
        float cs = 0.f, cd = 0.f;
        for (int c = 0; c < F_O; ++c) { cs += b2[c] * a2s[c]; cd += b2[c] * a2d[c]; }
        csb[0] = cs; csb[1] = cd;
    }
}

// ---------------- GEMM1 (MFMA): h1 = f16(x @ W1), fused fp32 alphas ----------------

__global__ __launch_bounds__(256, 2) void k_gemm1m(const float* __restrict__ x,
                                                   const unsigned short* __restrict__ WhiT,
                                                   const unsigned short* __restrict__ WloT,
                                                   const float* __restrict__ avs,
                                                   const float* __restrict__ avd,
                                                   unsigned short* __restrict__ h,
                                                   float* __restrict__ as,
                                                   float* __restrict__ ad, int N) {
    __shared__ __align__(16) float xs[64][132];    // 33.8 KB; aliased as hs below
    unsigned short (*hs)[72] = (unsigned short(*)[72])xs;
    const int t = threadIdx.x;
    const int wv = t >> 6;
    const int lane = t & 63;
    const int lrow = lane & 15;
    const int lk8 = lane >> 4;
    const int r0 = blockIdx.x * 64;

    // coalesced stage: 64 rows x 32 float4 = 2048 float4, 8 per thread
    {
        const float4* xg = (const float4*)x;
#pragma unroll
        for (int it = 0; it < 8; ++it) {
            int flat = it * 256 + t;               // 0..2047
            int row = flat >> 5, c4 = flat & 31;
            int grow = min(r0 + row, N - 1);
            float4 v = xg[(size_t)grow * 32 + c4];
            *(float4*)&xs[row][c4 * 4] = v;
        }
    }

    // preload ALL B-frags (block-invariant tables, L2-hot) while x stages
    s16x8 bh[4][4], bl[4][4];
#pragma unroll
    for (int kt = 0; kt < 4; ++kt)
#pragma unroll
        for (int ct = 0; ct < 4; ++ct) {
            const int boff = (ct * 16 + lrow) * F_IN + kt * 32 + lk8 * 8;
            bh[kt][ct] = *(const s16x8*)&WhiT[boff];
            bl[kt][ct] = *(const s16x8*)&WloT[boff];
        }
    __syncthreads();

    // frag load from LDS + split to bf16 hi/lo
    s16x8 ah[4], al[4];
#pragma unroll
    for (int kt = 0; kt < 4; ++kt) {
        const float* rp_ = &xs[wv * 16 + lrow][kt * 32 + lk8 * 8];
        float4 a = *(const float4*)rp_;
        float4 b = *(const float4*)(rp_ + 4);
        float e0[8] = {a.x, a.y, a.z, a.w, b.x, b.y, b.z, b.w};
        unsigned uh[4], ul[4];
#pragma unroll
        for (int p = 0; p < 4; ++p) {
            float a0 = e0[2 * p], a1 = e0[2 * p + 1];
            unsigned u0 = __float_as_uint(a0), u1 = __float_as_uint(a1);
            float d0 = a0 - __uint_as_float(u0 & 0xFFFF0000u);
            float d1 = a1 - __uint_as_float(u1 & 0xFFFF0000u);
            uh[p] = __builtin_amdgcn_perm(u1, u0, 0x07060302u);
            ul[p] = __builtin_amdgcn_perm(__float_as_uint(d1), __float_as_uint(d0), 0x07060302u);
        }
        ah[kt] = __builtin_bit_cast(s16x8, make_uint4(uh[0], uh[1], uh[2], uh[3]));
        al[kt] = __builtin_bit_cast(s16x8, make_uint4(ul[0], ul[1], ul[2], ul[3]));
    }
    __syncthreads();                               // xs reads done -> reuse as hs

    f32x4 acc[4] = {};                             // one 16x16 C-tile per ct
#pragma unroll
    for (int kt = 0; kt < 4; ++kt) {
#pragma unroll
        for (int ct = 0; ct < 4; ++ct) {
            acc[ct] = __builtin_amdgcn_mfma_f32_16x16x32_bf16(ah[kt], bh[kt][ct], acc[ct], 0, 0, 0);
            acc[ct] = __builtin_amdgcn_mfma_f32_16x16x32_bf16(al[kt], bh[kt][ct], acc[ct], 0, 0, 0);
            acc[ct] = __builtin_amdgcn_mfma_f32_16x16x32_bf16(ah[kt], bl[kt][ct], acc[ct], 0, 0, 0);
        }
    }

    // fused alphas from fp32 accumulators: reduce over 16 cols (lrow groups)
    float avs_c[4], avd_c[4];
#pragma unroll
    for (int ct = 0; ct < 4; ++ct) {
        avs_c[ct] = avs[ct * 16 + lrow];
        avd_c[ct] = avd[ct * 16 + lrow];
    }
#pragma unroll
    for (int r = 0; r < 4; ++r) {
        float ps = acc[0][r] * avs_c[0] + acc[1][r] * avs_c[1]
                 + acc[2][r] * avs_c[2] + acc[3][r] * avs_c[3];
        float pd = acc[0][r] * avd_c[0] + acc[1][r] * avd_c[1]
                 + acc[2][r] * avd_c[2] + acc[3][r] * avd_c[3];
#pragma unroll
        for (int o = 8; o; o >>= 1) {
            ps += __shfl_xor(ps, o, 16);
            pd += __shfl_xor(pd, o, 16);
        }
        int orow = r0 + wv * 16 + lk8 * 4 + r;
        if (lrow == 0 && orow < N) { as[orow] = ps; ad[orow] = pd; }
    }

    // C -> LDS (f16) -> coalesced global store
#pragma unroll
    for (int ct = 0; ct < 4; ++ct)
#pragma unroll
        for (int r = 0; r < 4; ++r)
            hs[wv * 16 + lk8 * 4 + r][ct * 16 + lrow] = f2h(acc[ct][r]);
    __syncthreads();
    const int row = t >> 2, ch = t & 3;
    const int grow = r0 + row;
    if (grow < N) {
        uint4 v0 = *(const uint4*)&hs[row][ch * 16];
        uint4 v1 = *(const uint4*)&hs[row][ch * 16 + 8];
        uint4* gp = (uint4*)(h + (size_t)grow * F_H + ch * 16);
        gp[0] = v0; gp[1] = v1;
    }
}

// ---------------- Aggregation: 8 lanes per dst node, 8 nodes per wave ----------------
// Octet loop: edge list padded to x8 (w=0, src=self), 8 gathers in flight,
// 128B-aligned h rows.
// MODE 0 (layer 1): gathers h1; epilogue r = relu(acc*inv + b1) -> f16 out1h
//   row, plus FUSED as2/ad2 = r.(W2 a2) + b2.a2 via precomputed wasL/wadL.
// MODE 1 (layer 2): gathers out1h; epilogue agg_o@W2 + b2 (W2^T in LDS,
//   group agg_o via same-wave LDS), then log_softmax over 40 cols.

template <int MODE>
__global__ __launch_bounds__(256) void k_agg(const int* __restrict__ rp,
                                             const int* __restrict__ csr,
                                             const float* __restrict__ as,
                                             const float* __restrict__ ad,
                                             const uint4* __restrict__ h4,
                                             const float* __restrict__ b1,
                                             unsigned short* __restrict__ out1h,
                                             const float* __restrict__ wasL,
                                             const float* __restrict__ wadL,
                                             const float* __restrict__ csb,
                                             float* __restrict__ as2,
                                             float* __restrict__ ad2,
                                             const float* __restrict__ W2,
                                             const float* __restrict__ b2,
                                             float* __restrict__ out2, int N) {
    constexpr int CAP = 64;                        // LDS-resident edges per node
    __shared__ __align__(16) uint2 wsb[4][8][CAP + 2];
    __shared__ __align__(16) float W2sT[MODE ? F_O * 68 : 1];  // [40][68] padded
    const int t = threadIdx.x;
    const int w = t >> 6;
    const int g = (t >> 3) & 7;
    const int c = t & 7;
    if (MODE) {                                    // stage W2 transposed (all threads, pre-exit)
        for (int idx = t; idx < F_H * F_O; idx += 256) {
            int k = idx / F_O, cc = idx - k * F_O;
            W2sT[cc * 68 + k] = W2[idx];
        }
        __syncthreads();
    }
    const int i = blockIdx.x * 32 + (t >> 3);
    if (i >= N) return;
    const int start = rp[i], end = rp[i + 1];
    const int deg = end - start;
    const int dm = min(deg, CAP);
    const int dmR8 = (dm + 7) & ~7;                // padded to x8 (<= CAP)
    const float adi = ad[i];

    // Phase A: compute edge weights into this group's LDS segment
    for (int idx = c; idx < dm; idx += 8) {
        int srcn = __builtin_nontemporal_load(&csr[start + idx]);
        float e = as[srcn] + adi;
        e = fmaxf(e, 0.2f * e);                    // leaky_relu
        wsb[w][g][idx] = make_uint2(__float_as_uint(__expf(e)), (unsigned)srcn);
    }
    {   // pad (at most 7 entries): w=0, src=self
        int idx = dm + c;
        if (idx < dmR8) wsb[w][g][idx] = make_uint2(0u, (unsigned)i);
    }

    // Phase B: octet loop (same-wave LDS, no barrier needed)
    const uint4* pw = (const uint4*)wsb[w][g];
    float acc[8] = {}, acc2[8] = {};
    float sacc = 0.f;
    const int noct = dmR8 >> 3;
    for (int q = 0; q < noct; ++q) {
        uint4 m0 = pw[4 * q];                      // (w0,s0,w1,s1)
        uint4 m1 = pw[4 * q + 1];                  // (w2,s2,w3,s3)
        uint4 m2 = pw[4 * q + 2];                  // (w4,s4,w5,s5)
        uint4 m3 = pw[4 * q + 3];                  // (w6,s6,w7,s7)
        uint4 hv0 = h4[((size_t)m0.y << 3) + c];
        uint4 hv1 = h4[((size_t)m0.w << 3) + c];
        uint4 hv2 = h4[((size_t)m1.y << 3) + c];
        uint4 hv3 = h4[((size_t)m1.w << 3) + c];
        uint4 hv4 = h4[((size_t)m2.y << 3) + c];
        uint4 hv5 = h4[((size_t)m2.w << 3) + c];
        uint4 hv6 = h4[((size_t)m3.y << 3) + c];
        uint4 hv7 = h4[((size_t)m3.w << 3) + c];
        float w0 = __uint_as_float(m0.x), w1 = __uint_as_float(m0.z);
        float w2 = __uint_as_float(m1.x), w3 = __uint_as_float(m1.z);
        float w4 = __uint_as_float(m2.x), w5 = __uint_as_float(m2.z);
        float w6 = __uint_as_float(m3.x), w7 = __uint_as_float(m3.z);
        sacc += ((w0 + w1) + (w2 + w3)) + ((w4 + w5) + (w6 + w7));
        h2 wp0 = __builtin_amdgcn_cvt_pkrtz(w0, w1);
        h2 wp1 = __builtin_amdgcn_cvt_pkrtz(w2, w3);
        h2 wp2 = __builtin_amdgcn_cvt_pkrtz(w4, w5);
        h2 wp3 = __builtin_amdgcn_cvt_pkrtz(w6, w7);
        acc[0] = fdot2f(wp0, pklo(hv1.x, hv0.x), acc[0]);
        acc[1] = fdot2f(wp0, pkhi(hv1.x, hv0.x), acc[1]);
        acc[2] = fdot2f(wp0, pklo(hv1.y, hv0.y), acc[2]);
        acc[3] = fdot2f(wp0, pkhi(hv1.y, hv0.y), acc[3]);
        acc[4] = fdot2f(wp0, pklo(hv1.z, hv0.z), acc[4]);
        acc[5] = fdot2f(wp0, pkhi(hv1.z, hv0.z), acc[5]);
        acc[6] = fdot2f(wp0, pklo(hv1.w, hv0.w), acc[6]);
        acc[7] = fdot2f(wp0, pkhi(hv1.w, hv0.w), acc[7]);
        acc2[0] = fdot2f(wp1, pklo(hv3.x, hv2.x), acc2[0]);
        acc2[1] = fdot2f(wp1, pkhi(hv3.x, hv2.x), acc2[1]);
        acc2[2] = fdot2f(wp1, pklo(hv3.y, hv2.y), acc2[2]);
        acc2[3] = fdot2f(wp1, pkhi(hv3.y, hv2.y), acc2[3]);
        acc2[4] = fdot2f(wp1, pklo(hv3.z, hv2.z), acc2[4]);
        acc2[5] = fdot2f(wp1, pkhi(hv3.z, hv2.z), acc2[5]);
        acc2[6] = fdot2f(wp1, pklo(hv3.w, hv2.w), acc2[6]);
        acc2[7] = fdot2f(wp1, pkhi(hv3.w, hv2.w), acc2[7]);
        acc[0] = fdot2f(wp2, pklo(hv5.x, hv4.x), acc[0]);
        acc[1] = fdot2f(wp2, pkhi(hv5.x, hv4.x), acc[1]);
        acc[2] = fdot2f(wp2, pklo(hv5.y, hv4.y), acc[2]);
        acc[3] = fdot2f(wp2, pkhi(hv5.y, hv4.y), acc[3]);
        acc[4] = fdot2f(wp2, pklo(hv5.z, hv4.z), acc[4]);
        acc[5] = fdot2f(wp2, pkhi(hv5.z, hv4.z), acc[5]);
        acc[6] = fdot2f(wp2, pklo(hv5.w, hv4.w), acc[6]);
        acc[7] = fdot2f(wp2, pkhi(hv5.w, hv4.w), acc[7]);
        acc2[0] = fdot2f(wp3, pklo(hv7.x, hv6.x), acc2[0]);
        acc2[1] = fdot2f(wp3, pkhi(hv7.x, hv6.x), acc2[1]);
        acc2[2] = fdot2f(wp3, pklo(hv7.y, hv6.y), acc2[2]);
        acc2[3] = fdot2f(wp3, pkhi(hv7.y, hv6.y), acc2[3]);
        acc2[4] = fdot2f(wp3, pklo(hv7.z, hv6.z), acc2[4]);
        acc2[5] = fdot2f(wp3, pkhi(hv7.z, hv6.z), acc2[5]);
        acc2[6] = fdot2f(wp3, pklo(hv7.w, hv6.w), acc2[6]);
        acc2[7] = fdot2f(wp3, pkhi(hv7.w, hv6.w), acc2[7]);
    }

    // rare overflow tail (deg > CAP): single-edge, dup-pair trick with (w,0)
    for (int j = start + dm; j < end; ++j) {
        int srcn = __builtin_nontemporal_load(&csr[j]);
        float e = as[srcn] + adi;
        e = fmaxf(e, 0.2f * e);
        float wv = __expf(e);
        sacc += wv;
        uint4 hv = h4[((size_t)srcn << 3) + c];
        h2 wp = __builtin_amdgcn_cvt_pkrtz(wv, 0.f);
        acc[0] = fdot2f(wp, pklo(hv.x, hv.x), acc[0]);
        acc[1] = fdot2f(wp, pkhi(hv.x, hv.x), acc[1]);
        acc[2] = fdot2f(wp, pklo(hv.y, hv.y), acc[2]);
        acc[3] = fdot2f(wp, pkhi(hv.y, hv.y), acc[3]);
        acc[4] = fdot2f(wp, pklo(hv.z, hv.z), acc[4]);
        acc[5] = fdot2f(wp, pkhi(hv.z, hv.z), acc[5]);
        acc[6] = fdot2f(wp, pklo(hv.w, hv.w), acc[6]);
        acc[7] = fdot2f(wp, pkhi(hv.w, hv.w), acc[7]);
    }

#pragma unroll
    for (int k = 0; k < 8; ++k) acc[k] += acc2[k];
    float inv = 1.f / sacc;                        // identical across the group

    if (MODE == 0) {
        // layer 1 epilogue: relu(acc*inv + b1) -> f16 row + fused as2/ad2
        float r[8];
#pragma unroll
        for (int k = 0; k < 8; ++k)
            r[k] = fmaxf(fmaf(acc[k], inv, b1[8 * c + k]), 0.f);
        unsigned u0 = (unsigned)f2h(r[0]) | ((unsigned)f2h(r[1]) << 16);
        unsigned u1 = (unsigned)f2h(r[2]) | ((unsigned)f2h(r[3]) << 16);
        unsigned u2 = (unsigned)f2h(r[4]) | ((unsigned)f2h(r[5]) << 16);
        unsigned u3 = (unsigned)f2h(r[6]) | ((unsigned)f2h(r[7]) << 16);
        *(uint4*)(out1h + (size_t)i * F_H + 8 * c) = make_uint4(u0, u1, u2, u3);
        // fused attention-2 logits: as2[i] = r . wasL + b2.a2s (and ad2)
        float4 wa0 = *(const float4*)&wasL[8 * c];
        float4 wa1 = *(const float4*)&wasL[8 * c + 4];
        float4 wd0 = *(const float4*)&wadL[8 * c];
        float4 wd1 = *(const float4*)&wadL[8 * c + 4];
        float ps = r[0] * wa0.x + r[1] * wa0.y + r[2] * wa0.z + r[3] * wa0.w
                 + r[4] * wa1.x + r[5] * wa1.y + r[6] * wa1.z + r[7] * wa1.w;
        float pd = r[0] * wd0.x + r[1] * wd0.y + r[2] * wd0.z + r[3] * wd0.w
                 + r[4] * wd1.x + r[5] * wd1.y + r[6] * wd1.z + r[7] * wd1.w;
#pragma unroll
        for (int o = 4; o; o >>= 1) {
            ps += __shfl_xor(ps, o, 8);
            pd += __shfl_xor(pd, o, 8);
        }
        if (c == 0) { as2[i] = ps + csb[0]; ad2[i] = pd + csb[1]; }
    } else {
        // layer 2 epilogue: agg_o @ W2 + b2, then log_softmax over 40 cols.
        float* gl = (float*)&wsb[w][g][0];         // reuse own group's segment
        ((float4*)gl)[2 * c]     = make_float4(acc[0] * inv, acc[1] * inv, acc[2] * inv, acc[3] * inv);
        ((float4*)gl)[2 * c + 1] = make_float4(acc[4] * inv, acc[5] * inv, acc[6] * inv, acc[7] * inv);
        // lane c computes output cols {c + 8m}, m = 0..4
        float v[5];
#pragma unroll
        for (int m = 0; m < 5; ++m) v[m] = b2[c + 8 * m];
#pragma unroll
        for (int m = 0; m < 5; ++m) {
            const float* wr = &W2sT[(c + 8 * m) * 68];
            float vm = v[m];
#pragma unroll
            for (int k4 = 0; k4 < 16; ++k4) {
                float4 a4 = ((const float4*)gl)[k4];
                float4 w4 = *(const float4*)&wr[k4 * 4];
                vm += a4.x * w4.x + a4.y * w4.y + a4.z * w4.z + a4.w * w4.w;
            }
            v[m] = vm;
        }
        float mx = fmaxf(fmaxf(fmaxf(v[0], v[1]), fmaxf(v[2], v[3])), v[4]);
#pragma unroll
        for (int o = 4; o; o >>= 1) mx = fmaxf(mx, __shfl_xor(mx, o, 8));
        float es = __expf(v[0] - mx) + __expf(v[1] - mx) + __expf(v[2] - mx)
                 + __expf(v[3] - mx) + __expf(v[4] - mx);
#pragma unroll
        for (int o = 4; o; o >>= 1) es += __shfl_xor(es, o, 8);
        float lse = mx + __logf(es);
        float* op = out2 + (size_t)i * F_O + c;
#pragma unroll
        for (int m = 0; m < 5; ++m)
            __builtin_nontemporal_store(v[m] - lse, op + 8 * m);
    }
}

// ---------------- launch ----------------

extern "C" void kernel_launch(void* const* d_in, const int* in_sizes, int n_in,
                              void* d_out, int out_size, void* d_ws, size_t ws_size,
                              hipStream_t stream) {
    const float* x   = (const float*)d_in[0];
    const int* edges = (const int*)d_in[1];
    const float* W1  = (const float*)d_in[2];
    const float* av_s1 = (const float*)d_in[3];
    const float* av_d1 = (const float*)d_in[4];
    const float* b1  = (const float*)d_in[5];
    const float* W2  = (const float*)d_in[6];
    const float* av_s2 = (const float*)d_in[7];
    const float* av_d2 = (const float*)d_in[8];
    const float* b2  = (const float*)d_in[9];
    float* out = (float*)d_out;

    const int N  = in_sizes[0] / F_IN;
    const int E  = in_sizes[1] / 2;
    const int Et = E + N;
    const int NB = (N + 255) >> 8;

    char* p = (char*)d_ws;
    auto alloc = [&](size_t bytes) {
        char* q = p;
        p += (bytes + 255) & ~(size_t)255;
        return (void*)q;
    };
    unsigned short* h1 = (unsigned short*)alloc((size_t)N * F_H * 2);     // f16 [N][64]
    unsigned short* out1h = (unsigned short*)alloc((size_t)N * F_H * 2);  // f16 agg1 output [N][64]
    float* as1    = (float*)alloc((size_t)N * 4);
    float* ad1    = (float*)alloc((size_t)N * 4);
    float* as2    = (float*)alloc((size_t)N * 4);
    float* ad2    = (float*)alloc((size_t)N * 4);
    int* rp       = (int*)alloc((size_t)(N + 1) * 4);
    int* bcnt     = (int*)alloc(NBMAX * 4);
    int* bbase    = (int*)alloc(NBMAX * 4);
    int* bcur     = (int*)alloc(NBMAX * 4);
    unsigned* binned = (unsigned*)alloc((size_t)Et * 4);
    int* csr      = (int*)alloc((size_t)Et * 4);
    unsigned short* WhiT = (unsigned short*)alloc((size_t)F_H * F_IN * 2);
    unsigned short* WloT = (unsigned short*)alloc((size_t)F_H * F_IN * 2);
    float* wasL   = (float*)alloc(F_H * 4);
    float* wadL   = (float*)alloc(F_H * 4);
    float* csb    = (float*)alloc(2 * 4);
    (void)n_in; (void)out_size; (void)ws_size;

    const int* srcs = edges;
    const int* dsts = edges + E;

    hipMemsetAsync(bcnt, 0, NBMAX * 4, stream);

    k_wsplit<<<(F_IN * F_H + 255) / 256, 256, 0, stream>>>(W1, WhiT, WloT);
    k_wprep<<<1, 64, 0, stream>>>(W2, av_s2, av_d2, b2, wasL, wadL, csb);
    k_binA<<<(Et + 2047) / 2048, 256, 0, stream>>>(dsts, bcnt, E, Et, NB);
    k_binB<<<1, NBMAX, 0, stream>>>(bcnt, bbase, bcur, rp, NB, N, Et);
    k_binC<<<(Et + CHUNK - 1) / CHUNK, 256, 0, stream>>>(srcs, dsts, bcur, binned, E, Et, NB);
    k_binD<<<NB, 256, 0, stream>>>(binned, bbase, bcur, rp, csr, N);

    k_gemm1m<<<(N + 63) / 64, 256, 0, stream>>>(x, WhiT, WloT, av_s1, av_d1, h1, as1, ad1, N);
    int gAgg = (N + 31) / 32;
    k_agg<0><<<gAgg, 256, 0, stream>>>(rp, csr, as1, ad1, (const uint4*)h1,
                                       b1, out1h, wasL, wadL, csb, as2, ad2,
                                       nullptr, nullptr, nullptr, N);
    k_agg<1><<<gAgg, 256, 0, stream>>>(rp, csr, as2, ad2, (const uint4*)out1h,
                                       nullptr, nullptr, nullptr, nullptr, nullptr,
                                       nullptr, nullptr, W2, b2, out, N);
}

// Round 13
// 277.773 us; speedup vs baseline: 1.0573x; 1.0192x over previous
//
#include <hip/hip_runtime.h>
#include <math.h>

// GAT 2-layer, N=100K nodes, E=1.6M edges (+N self loops), fp32 compute,
// f16 feature rows for the edge gather.
// CSR build via 2-level bucket sort (bucket = dst>>8); binD orders each
// node's list by src-chunk (kept, free).
// agg: 8 lanes per dst node, 8 nodes per wave, octet unroll, f16 pair-dot,
//   128B-aligned [N][64] f16 rows. Gather is at the compulsory cross-XCD
//   random-line floor (~87MB at ~2.6TB/s; invariant across 8 levers r2-r10).
// GEMM2 eliminated by algebra (r11): out2 = (sum coef*out1)@W2 + b2.
//   r12: MODE1 epilogue cost cut -- W2 staged as PACKED-F16 [40][34] u32
//   (5.4KB LDS, was 10.9 fp32 -> occupancy 5->7 blocks/CU), group agg vector
//   written to LDS as packed f16 (conflict-aligned uint4/lane), matmul via
//   160 v_dot2_f32_f16 (was 320 FMA + float4 LDS traffic). r11 counters:
//   occ 47->37%, bank-conflicts 123K->873K were the 41->49us regression.
// gemm1 MFMA 3-pass truncation-split bf16, B-frags preloaded to registers.
// r13: fix r12 compile error -- k_agg<1> launch was missing the ad2 nullptr
//   (15 of 16 args). No design change.

constexpr int F_IN = 128;
constexpr int F_H  = 64;
constexpr int F_O  = 40;
constexpr int NBMAX = 512;      // max buckets (N <= 131072)
constexpr int CHUNK = 8192;     // edges per block in k_binC
constexpr int NKEY  = 2048;     // 256 nodes x 8 src-chunks (binD)

using h2 = decltype(__builtin_amdgcn_cvt_pkrtz(0.f, 0.f));   // <2 x half>
typedef __attribute__((ext_vector_type(4))) float f32x4;
typedef __attribute__((ext_vector_type(8))) short s16x8;

__device__ __forceinline__ h2 u2h(unsigned u) { return __builtin_bit_cast(h2, u); }
__device__ __forceinline__ unsigned h2u(h2 h) { return __builtin_bit_cast(unsigned, h); }

__device__ __forceinline__ float fdot2f(h2 a, h2 b, float c) {
#if __has_builtin(__builtin_amdgcn_fdot2)
    return __builtin_amdgcn_fdot2(a, b, c, false);      // v_dot2_f32_f16
#else
    return c + (float)a.x * (float)b.x + (float)a.y * (float)b.y;
#endif
}
// interleave two u32s of packed f16 pairs: pklo -> (b.lo16, a.lo16), pkhi -> (b.hi16, a.hi16)
__device__ __forceinline__ h2 pklo(unsigned a, unsigned b) {
    return u2h(__builtin_amdgcn_perm(a, b, 0x05040100u));
}
__device__ __forceinline__ h2 pkhi(unsigned a, unsigned b) {
    return u2h(__builtin_amdgcn_perm(a, b, 0x07060302u));
}
__device__ __forceinline__ unsigned short f2h(float f) {   // RNE f32->f16 bits
    _Float16 x = (_Float16)f;
    return __builtin_bit_cast(unsigned short, x);
}

// ---------------- CSR build: bucket sort ----------------

__global__ __launch_bounds__(256) void k_binA(const int* __restrict__ dsts,
                                              int* __restrict__ bcnt,
                                              int E, int Et, int NB) {
    __shared__ int hist[NBMAX];
    for (int i = threadIdx.x; i < NB; i += 256) hist[i] = 0;
    __syncthreads();
    int e0 = blockIdx.x * 2048;
#pragma unroll
    for (int it = 0; it < 8; ++it) {
        int e = e0 + it * 256 + threadIdx.x;
        if (e < Et) {
            int d = (e < E) ? dsts[e] : (e - E);
            atomicAdd(&hist[d >> 8], 1);
        }
    }
    __syncthreads();
    for (int i = threadIdx.x; i < NB; i += 256) {
        int c = hist[i];
        if (c) atomicAdd(&bcnt[i], c);
    }
}

__global__ __launch_bounds__(NBMAX) void k_binB(const int* __restrict__ bcnt,
                                                int* __restrict__ bbase,
                                                int* __restrict__ bcur,
                                                int* __restrict__ rp,
                                                int NB, int N, int Et) {
    __shared__ int sc[NBMAX];
    int t = threadIdx.x;
    int v = (t < NB) ? bcnt[t] : 0;
    sc[t] = v; __syncthreads();
    int x = v;
    for (int o = 1; o < NBMAX; o <<= 1) {
        int y = (t >= o) ? sc[t - o] : 0;
        __syncthreads();
        x += y;
        sc[t] = x;
        __syncthreads();
    }
    if (t < NB) { int b = x - v; bbase[t] = b; bcur[t] = b; }
    if (t == 0) rp[N] = Et;
}

__global__ __launch_bounds__(256) void k_binC(const int* __restrict__ srcs,
                                              const int* __restrict__ dsts,
                                              int* __restrict__ bcur,
                                              unsigned* __restrict__ binned,
                                              int E, int Et, int NB) {
    __shared__ int hist[NBMAX];
    __shared__ int gbase[NBMAX];
    __shared__ int lcnt[NBMAX];
    int t = threadIdx.x;
    for (int i = t; i < NB; i += 256) hist[i] = 0;
    __syncthreads();
    int e0 = blockIdx.x * CHUNK;
#pragma unroll 4
    for (int it = 0; it < CHUNK / 256; ++it) {
        int e = e0 + it * 256 + t;
        if (e < Et) {
            int d = (e < E) ? dsts[e] : (e - E);
            atomicAdd(&hist[d >> 8], 1);
        }
    }
    __syncthreads();
    for (int i = t; i < NB; i += 256) {
        int c = hist[i];
        gbase[i] = c ? atomicAdd(&bcur[i], c) : 0;
        lcnt[i] = 0;
    }
    __syncthreads();
#pragma unroll 4
    for (int it = 0; it < CHUNK / 256; ++it) {
        int e = e0 + it * 256 + t;
        if (e < Et) {
            int s, d;
            if (e < E) { s = srcs[e]; d = dsts[e]; } else { s = e - E; d = s; }
            int b = d >> 8;
            int p = atomicAdd(&lcnt[b], 1);
            binned[gbase[b] + p] = (unsigned)s | ((unsigned)(d & 255) << 24);
        }
    }
}

// binD: within each 256-node bucket, order by key = (dst&255)*8 | src>>14.

__global__ __launch_bounds__(256) void k_binD(const unsigned* __restrict__ binned,
                                              const int* __restrict__ bbase,
                                              const int* __restrict__ bcur,
                                              int* __restrict__ rp,
                                              int* __restrict__ csr, int N) {
    __shared__ int hist[NKEY];
    __shared__ int sc2[NKEY];
    __shared__ int lcnt[NKEY];
    __shared__ int tsum[256];
    int b = blockIdx.x, t = threadIdx.x;
    int base = bbase[b], end = bcur[b];
    for (int k = t; k < NKEY; k += 256) { hist[k] = 0; lcnt[k] = 0; }
    __syncthreads();
    for (int j = base + t; j < end; j += 256) {
        unsigned w = binned[j];
        int key = ((int)(w >> 24) << 3) | (int)((w & 0xFFFFFFu) >> 14);
        atomicAdd(&hist[key], 1);
    }
    __syncthreads();
    int myk = t << 3;
    int s = 0;
#pragma unroll
    for (int k = 0; k < 8; ++k) s += hist[myk + k];
    tsum[t] = s; __syncthreads();
    int x = s;
    for (int o = 1; o < 256; o <<= 1) {
        int y = (t >= o) ? tsum[t - o] : 0;
        __syncthreads();
        x += y;
        tsum[t] = x;
        __syncthreads();
    }
    int run = x - s;                               // exclusive prefix (thread = node)
    int g = (b << 8) + t;
    if (g < N) rp[g] = base + run;
#pragma unroll
    for (int k = 0; k < 8; ++k) { sc2[myk + k] = run; run += hist[myk + k]; }
    __syncthreads();
    for (int j = base + t; j < end; j += 256) {
        unsigned w = binned[j];
        int src = (int)(w & 0xFFFFFFu);
        int key = ((int)(w >> 24) << 3) | (src >> 14);
        int p = atomicAdd(&lcnt[key], 1);
        csr[base + sc2[key] + p] = src;
    }
}

// ---------------- prep: W1 split + W2 pack + attention-2 vectors ----------------
// W1: fp32 [128][64] -> bf16-hi/lo transposed [64][128].
// W2p: packed f16 pairs, W2p[cc*34 + k2] = (W2[2k2][cc], W2[2k2+1][cc]).
// wasL/wadL = W2 @ a2s / W2 @ a2d (64-vecs); csb = (b2.a2s, b2.a2d).

__global__ __launch_bounds__(256) void k_prep(const float* __restrict__ W1,
                                              unsigned short* __restrict__ WhiT,
                                              unsigned short* __restrict__ WloT,
                                              const float* __restrict__ W2,
                                              const float* __restrict__ a2s,
                                              const float* __restrict__ a2d,
                                              const float* __restrict__ b2,
                                              unsigned* __restrict__ W2p,
                                              float* __restrict__ wasL,
                                              float* __restrict__ wadL,
                                              float* __restrict__ csb) {
    int i = blockIdx.x * 256 + threadIdx.x;
    if (i < F_IN * F_H) {
        int k = i >> 6, c = i & 63;                // W1[k][c]
        float w = W1[i];
        unsigned u = __float_as_uint(w);
        unsigned hi = u & 0xFFFF0000u;
        float d = w - __uint_as_float(hi);
        WhiT[c * F_IN + k] = (unsigned short)(hi >> 16);
        WloT[c * F_IN + k] = (unsigned short)(__float_as_uint(d) >> 16);
    }
    if (i < F_O * 32) {                            // 40 cols x 32 k-pairs
        int cc = i >> 5, k2 = i & 31;
        W2p[cc * 34 + k2] = h2u(__builtin_amdgcn_cvt_pkrtz(
            W2[(2 * k2) * F_O + cc], W2[(2 * k2 + 1) * F_O + cc]));
    }
    if (i < F_H) {
        float s = 0.f, d = 0.f;
        for (int c = 0; c < F_O; ++c) {
            float w = W2[i * F_O + c];
            s += w * a2s[c];
            d += w * a2d[c];
        }
        wasL[i] = s;
        wadL[i] = d;
    }
    if (i == 0) {
        float cs = 0.f, cd = 0.f;
        for (int c = 0; c < F_O; ++c) { cs += b2[c] * a2s[c]; cd += b2[c] * a2d[c]; }
        csb[0] = cs; csb[1] = cd;
    }
}

// ---------------- GEMM1 (MFMA): h1 = f16(x @ W1), fused fp32 alphas ----------------

__global__ __launch_bounds__(256, 2) void k_gemm1m(const float* __restrict__ x,
                                                   const unsigned short* __restrict__ WhiT,
                                                   const unsigned short* __restrict__ WloT,
                                                   const float* __restrict__ avs,
                                                   const float* __restrict__ avd,
                                                   unsigned short* __restrict__ h,
                                                   float* __restrict__ as,
                                                   float* __restrict__ ad, int N) {
    __shared__ __align__(16) float xs[64][132];    // 33.8 KB; aliased as hs below
    unsigned short (*hs)[72] = (unsigned short(*)[72])xs;
    const int t = threadIdx.x;
    const int wv = t >> 6;
    const int lane = t & 63;
    const int lrow = lane & 15;
    const int lk8 = lane >> 4;
    const int r0 = blockIdx.x * 64;

    // coalesced stage: 64 rows x 32 float4 = 2048 float4, 8 per thread
    {
        const float4* xg = (const float4*)x;
#pragma unroll
        for (int it = 0; it < 8; ++it) {
            int flat = it * 256 + t;               // 0..2047
            int row = flat >> 5, c4 = flat & 31;
            int grow = min(r0 + row, N - 1);
            float4 v = xg[(size_t)grow * 32 + c4];
            *(float4*)&xs[row][c4 * 4] = v;
        }
    }

    // preload ALL B-frags (block-invariant tables, L2-hot) while x stages
    s16x8 bh[4][4], bl[4][4];
#pragma unroll
    for (int kt = 0; kt < 4; ++kt)
#pragma unroll
        for (int ct = 0; ct < 4; ++ct) {
            const int boff = (ct * 16 + lrow) * F_IN + kt * 32 + lk8 * 8;
            bh[kt][ct] = *(const s16x8*)&WhiT[boff];
            bl[kt][ct] = *(const s16x8*)&WloT[boff];
        }
    __syncthreads();

    // frag load from LDS + split to bf16 hi/lo
    s16x8 ah[4], al[4];
#pragma unroll
    for (int kt = 0; kt < 4; ++kt) {
        const float* rp_ = &xs[wv * 16 + lrow][kt * 32 + lk8 * 8];
        float4 a = *(const float4*)rp_;
        float4 b = *(const float4*)(rp_ + 4);
        float e0[8] = {a.x, a.y, a.z, a.w, b.x, b.y, b.z, b.w};
        unsigned uh[4], ul[4];
#pragma unroll
        for (int p = 0; p < 4; ++p) {
            float a0 = e0[2 * p], a1 = e0[2 * p + 1];
            unsigned u0 = __float_as_uint(a0), u1 = __float_as_uint(a1);
            float d0 = a0 - __uint_as_float(u0 & 0xFFFF0000u);
            float d1 = a1 - __uint_as_float(u1 & 0xFFFF0000u);
            uh[p] = __builtin_amdgcn_perm(u1, u0, 0x07060302u);
            ul[p] = __builtin_amdgcn_perm(__float_as_uint(d1), __float_as_uint(d0), 0x07060302u);
        }
        ah[kt] = __builtin_bit_cast(s16x8, make_uint4(uh[0], uh[1], uh[2], uh[3]));
        al[kt] = __builtin_bit_cast(s16x8, make_uint4(ul[0], ul[1], ul[2], ul[3]));
    }
    __syncthreads();                               // xs reads done -> reuse as hs

    f32x4 acc[4] = {};                             // one 16x16 C-tile per ct
#pragma unroll
    for (int kt = 0; kt < 4; ++kt) {
#pragma unroll
        for (int ct = 0; ct < 4; ++ct) {
            acc[ct] = __builtin_amdgcn_mfma_f32_16x16x32_bf16(ah[kt], bh[kt][ct], acc[ct], 0, 0, 0);
            acc[ct] = __builtin_amdgcn_mfma_f32_16x16x32_bf16(al[kt], bh[kt][ct], acc[ct], 0, 0, 0);
            acc[ct] = __builtin_amdgcn_mfma_f32_16x16x32_bf16(ah[kt], bl[kt][ct], acc[ct], 0, 0, 0);
        }
    }

    // fused alphas from fp32 accumulators: reduce over 16 cols (lrow groups)
    float avs_c[4], avd_c[4];
#pragma unroll
    for (int ct = 0; ct < 4; ++ct) {
        avs_c[ct] = avs[ct * 16 + lrow];
        avd_c[ct] = avd[ct * 16 + lrow];
    }
#pragma unroll
    for (int r = 0; r < 4; ++r) {
        float ps = acc[0][r] * avs_c[0] + acc[1][r] * avs_c[1]
                 + acc[2][r] * avs_c[2] + acc[3][r] * avs_c[3];
        float pd = acc[0][r] * avd_c[0] + acc[1][r] * avd_c[1]
                 + acc[2][r] * avd_c[2] + acc[3][r] * avd_c[3];
#pragma unroll
        for (int o = 8; o; o >>= 1) {
            ps += __shfl_xor(ps, o, 16);
            pd += __shfl_xor(pd, o, 16);
        }
        int orow = r0 + wv * 16 + lk8 * 4 + r;
        if (lrow == 0 && orow < N) { as[orow] = ps; ad[orow] = pd; }
    }

    // C -> LDS (f16) -> coalesced global store
#pragma unroll
    for (int ct = 0; ct < 4; ++ct)
#pragma unroll
        for (int r = 0; r < 4; ++r)
            hs[wv * 16 + lk8 * 4 + r][ct * 16 + lrow] = f2h(acc[ct][r]);
    __syncthreads();
    const int row = t >> 2, ch = t & 3;
    const int grow = r0 + row;
    if (grow < N) {
        uint4 v0 = *(const uint4*)&hs[row][ch * 16];
        uint4 v1 = *(const uint4*)&hs[row][ch * 16 + 8];
        uint4* gp = (uint4*)(h + (size_t)grow * F_H + ch * 16);
        gp[0] = v0; gp[1] = v1;
    }
}

// ---------------- Aggregation: 8 lanes per dst node, 8 nodes per wave ----------------
// Octet loop: edge list padded to x8 (w=0, src=self), 8 gathers in flight,
// 128B-aligned h rows.
// MODE 0 (layer 1): gathers h1; epilogue r = relu(acc*inv + b1) -> f16 out1h
//   row, plus FUSED as2/ad2 = r.(W2 a2) + b2.a2 via precomputed wasL/wadL.
// MODE 1 (layer 2): gathers out1h; epilogue: group agg vector packed to f16
//   in own LDS segment, matmul vs packed-f16 W2 (LDS, 5.4KB) via
//   v_dot2_f32_f16, then log_softmax over 40 cols.

template <int MODE>
__global__ __launch_bounds__(256) void k_agg(const int* __restrict__ rp,
                                             const int* __restrict__ csr,
                                             const float* __restrict__ as,
                                             const float* __restrict__ ad,
                                             const uint4* __restrict__ h4,
                                             const float* __restrict__ b1,
                                             unsigned short* __restrict__ out1h,
                                             const float* __restrict__ wasL,
                                             const float* __restrict__ wadL,
                                             const float* __restrict__ csb,
                                             float* __restrict__ as2,
                                             float* __restrict__ ad2,
                                             const unsigned* __restrict__ W2p,
                                             const float* __restrict__ b2,
                                             float* __restrict__ out2, int N) {
    constexpr int CAP = 64;                        // LDS-resident edges per node
    __shared__ __align__(16) uint2 wsb[4][8][CAP + 2];
    __shared__ __align__(16) unsigned W2s[MODE ? F_O * 34 : 1];  // packed f16 pairs
    const int t = threadIdx.x;
    const int w = t >> 6;
    const int g = (t >> 3) & 7;
    const int c = t & 7;
    if (MODE) {                                    // stage packed W2 (pre-exit)
        for (int idx = t; idx < F_O * 34; idx += 256)
            W2s[idx] = W2p[idx];
        __syncthreads();
    }
    const int i = blockIdx.x * 32 + (t >> 3);
    if (i >= N) return;
    const int start = rp[i], end = rp[i + 1];
    const int deg = end - start;
    const int dm = min(deg, CAP);
    const int dmR8 = (dm + 7) & ~7;                // padded to x8 (<= CAP)
    const float adi = ad[i];

    // Phase A: compute edge weights into this group's LDS segment
    for (int idx = c; idx < dm; idx += 8) {
        int srcn = __builtin_nontemporal_load(&csr[start + idx]);
        float e = as[srcn] + adi;
        e = fmaxf(e, 0.2f * e);                    // leaky_relu
        wsb[w][g][idx] = make_uint2(__float_as_uint(__expf(e)), (unsigned)srcn);
    }
    {   // pad (at most 7 entries): w=0, src=self
        int idx = dm + c;
        if (idx < dmR8) wsb[w][g][idx] = make_uint2(0u, (unsigned)i);
    }

    // Phase B: octet loop (same-wave LDS, no barrier needed)
    const uint4* pw = (const uint4*)wsb[w][g];
    float acc[8] = {}, acc2[8] = {};
    float sacc = 0.f;
    const int noct = dmR8 >> 3;
    for (int q = 0; q < noct; ++q) {
        uint4 m0 = pw[4 * q];                      // (w0,s0,w1,s1)
        uint4 m1 = pw[4 * q + 1];                  // (w2,s2,w3,s3)
        uint4 m2 = pw[4 * q + 2];                  // (w4,s4,w5,s5)
        uint4 m3 = pw[4 * q + 3];                  // (w6,s6,w7,s7)
        uint4 hv0 = h4[((size_t)m0.y << 3) + c];
        uint4 hv1 = h4[((size_t)m0.w << 3) + c];
        uint4 hv2 = h4[((size_t)m1.y << 3) + c];
        uint4 hv3 = h4[((size_t)m1.w << 3) + c];
        uint4 hv4 = h4[((size_t)m2.y << 3) + c];
        uint4 hv5 = h4[((size_t)m2.w << 3) + c];
        uint4 hv6 = h4[((size_t)m3.y << 3) + c];
        uint4 hv7 = h4[((size_t)m3.w << 3) + c];
        float w0 = __uint_as_float(m0.x), w1 = __uint_as_float(m0.z);
        float w2 = __uint_as_float(m1.x), w3 = __uint_as_float(m1.z);
        float w4 = __uint_as_float(m2.x), w5 = __uint_as_float(m2.z);
        float w6 = __uint_as_float(m3.x), w7 = __uint_as_float(m3.z);
        sacc += ((w0 + w1) + (w2 + w3)) + ((w4 + w5) + (w6 + w7));
        h2 wp0 = __builtin_amdgcn_cvt_pkrtz(w0, w1);
        h2 wp1 = __builtin_amdgcn_cvt_pkrtz(w2, w3);
        h2 wp2 = __builtin_amdgcn_cvt_pkrtz(w4, w5);
        h2 wp3 = __builtin_amdgcn_cvt_pkrtz(w6, w7);
        acc[0] = fdot2f(wp0, pklo(hv1.x, hv0.x), acc[0]);
        acc[1] = fdot2f(wp0, pkhi(hv1.x, hv0.x), acc[1]);
        acc[2] = fdot2f(wp0, pklo(hv1.y, hv0.y), acc[2]);
        acc[3] = fdot2f(wp0, pkhi(hv1.y, hv0.y), acc[3]);
        acc[4] = fdot2f(wp0, pklo(hv1.z, hv0.z), acc[4]);
        acc[5] = fdot2f(wp0, pkhi(hv1.z, hv0.z), acc[5]);
        acc[6] = fdot2f(wp0, pklo(hv1.w, hv0.w), acc[6]);
        acc[7] = fdot2f(wp0, pkhi(hv1.w, hv0.w), acc[7]);
        acc2[0] = fdot2f(wp1, pklo(hv3.x, hv2.x), acc2[0]);
        acc2[1] = fdot2f(wp1, pkhi(hv3.x, hv2.x), acc2[1]);
        acc2[2] = fdot2f(wp1, pklo(hv3.y, hv2.y), acc2[2]);
        acc2[3] = fdot2f(wp1, pkhi(hv3.y, hv2.y), acc2[3]);
        acc2[4] = fdot2f(wp1, pklo(hv3.z, hv2.z), acc2[4]);
        acc2[5] = fdot2f(wp1, pkhi(hv3.z, hv2.z), acc2[5]);
        acc2[6] = fdot2f(wp1, pklo(hv3.w, hv2.w), acc2[6]);
        acc2[7] = fdot2f(wp1, pkhi(hv3.w, hv2.w), acc2[7]);
        acc[0] = fdot2f(wp2, pklo(hv5.x, hv4.x), acc[0]);
        acc[1] = fdot2f(wp2, pkhi(hv5.x, hv4.x), acc[1]);
        acc[2] = fdot2f(wp2, pklo(hv5.y, hv4.y), acc[2]);
        acc[3] = fdot2f(wp2, pkhi(hv5.y, hv4.y), acc[3]);
        acc[4] = fdot2f(wp2, pklo(hv5.z, hv4.z), acc[4]);
        acc[5] = fdot2f(wp2, pkhi(hv5.z, hv4.z), acc[5]);
        acc[6] = fdot2f(wp2, pklo(hv5.w, hv4.w), acc[6]);
        acc[7] = fdot2f(wp2, pkhi(hv5.w, hv4.w), acc[7]);
        acc2[0] = fdot2f(wp3, pklo(hv7.x, hv6.x), acc2[0]);
        acc2[1] = fdot2f(wp3, pkhi(hv7.x, hv6.x), acc2[1]);
        acc2[2] = fdot2f(wp3, pklo(hv7.y, hv6.y), acc2[2]);
        acc2[3] = fdot2f(wp3, pkhi(hv7.y, hv6.y), acc2[3]);
        acc2[4] = fdot2f(wp3, pklo(hv7.z, hv6.z), acc2[4]);
        acc2[5] = fdot2f(wp3, pkhi(hv7.z, hv6.z), acc2[5]);
        acc2[6] = fdot2f(wp3, pklo(hv7.w, hv6.w), acc2[6]);
        acc2[7] = fdot2f(wp3, pkhi(hv7.w, hv6.w), acc2[7]);
    }

    // rare overflow tail (deg > CAP): single-edge, dup-pair trick with (w,0)
    for (int j = start + dm; j < end; ++j) {
        int srcn = __builtin_nontemporal_load(&csr[j]);
        float e = as[srcn] + adi;
        e = fmaxf(e, 0.2f * e);
        float wv = __expf(e);
        sacc += wv;
        uint4 hv = h4[((size_t)srcn << 3) + c];
        h2 wp = __builtin_amdgcn_cvt_pkrtz(wv, 0.f);
        acc[0] = fdot2f(wp, pklo(hv.x, hv.x), acc[0]);
        acc[1] = fdot2f(wp, pkhi(hv.x, hv.x), acc[1]);
        acc[2] = fdot2f(wp, pklo(hv.y, hv.y), acc[2]);
        acc[3] = fdot2f(wp, pkhi(hv.y, hv.y), acc[3]);
        acc[4] = fdot2f(wp, pklo(hv.z, hv.z), acc[4]);
        acc[5] = fdot2f(wp, pkhi(hv.z, hv.z), acc[5]);
        acc[6] = fdot2f(wp, pklo(hv.w, hv.w), acc[6]);
        acc[7] = fdot2f(wp, pkhi(hv.w, hv.w), acc[7]);
    }

#pragma unroll
    for (int k = 0; k < 8; ++k) acc[k] += acc2[k];
    float inv = 1.f / sacc;                        // identical across the group

    if (MODE == 0) {
        // layer 1 epilogue: relu(acc*inv + b1) -> f16 row + fused as2/ad2
        float r[8];
#pragma unroll
        for (int k = 0; k < 8; ++k)
            r[k] = fmaxf(fmaf(acc[k], inv, b1[8 * c + k]), 0.f);
        unsigned u0 = (unsigned)f2h(r[0]) | ((unsigned)f2h(r[1]) << 16);
        unsigned u1 = (unsigned)f2h(r[2]) | ((unsigned)f2h(r[3]) << 16);
        unsigned u2 = (unsigned)f2h(r[4]) | ((unsigned)f2h(r[5]) << 16);
        unsigned u3 = (unsigned)f2h(r[6]) | ((unsigned)f2h(r[7]) << 16);
        *(uint4*)(out1h + (size_t)i * F_H + 8 * c) = make_uint4(u0, u1, u2, u3);
        // fused attention-2 logits: as2[i] = r . wasL + b2.a2s (and ad2)
        float4 wa0 = *(const float4*)&wasL[8 * c];
        float4 wa1 = *(const float4*)&wasL[8 * c + 4];
        float4 wd0 = *(const float4*)&wadL[8 * c];
        float4 wd1 = *(const float4*)&wadL[8 * c + 4];
        float ps = r[0] * wa0.x + r[1] * wa0.y + r[2] * wa0.z + r[3] * wa0.w
                 + r[4] * wa1.x + r[5] * wa1.y + r[6] * wa1.z + r[7] * wa1.w;
        float pd = r[0] * wd0.x + r[1] * wd0.y + r[2] * wd0.z + r[3] * wd0.w
                 + r[4] * wd1.x + r[5] * wd1.y + r[6] * wd1.z + r[7] * wd1.w;
#pragma unroll
        for (int o = 4; o; o >>= 1) {
            ps += __shfl_xor(ps, o, 8);
            pd += __shfl_xor(pd, o, 8);
        }
        if (c == 0) { as2[i] = ps + csb[0]; ad2[i] = pd + csb[1]; }
    } else {
        // layer 2 epilogue: agg (packed f16 in own LDS segment) @ W2p + b2,
        // then log_softmax over 40 cols. All via v_dot2_f32_f16, fp32 accum.
        unsigned* gl = (unsigned*)&wsb[w][g][0];   // 32 u32 = 64 packed f16
        uint4 pk;
        pk.x = h2u(__builtin_amdgcn_cvt_pkrtz(acc[0] * inv, acc[1] * inv));
        pk.y = h2u(__builtin_amdgcn_cvt_pkrtz(acc[2] * inv, acc[3] * inv));
        pk.z = h2u(__builtin_amdgcn_cvt_pkrtz(acc[4] * inv, acc[5] * inv));
        pk.w = h2u(__builtin_amdgcn_cvt_pkrtz(acc[6] * inv, acc[7] * inv));
        ((uint4*)gl)[c] = pk;                      // features 8c..8c+7 (same-wave)
        // lane c computes output cols {c + 8m}, m = 0..4
        float v[5];
#pragma unroll
        for (int m = 0; m < 5; ++m) v[m] = b2[c + 8 * m];
        for (int k2 = 0; k2 < 32; ++k2) {
            h2 a2 = u2h(gl[k2]);                   // broadcast within group
#pragma unroll
            for (int m = 0; m < 5; ++m)
                v[m] = fdot2f(a2, u2h(W2s[(c + 8 * m) * 34 + k2]), v[m]);
        }
        float mx = fmaxf(fmaxf(fmaxf(v[0], v[1]), fmaxf(v[2], v[3])), v[4]);
#pragma unroll
        for (int o = 4; o; o >>= 1) mx = fmaxf(mx, __shfl_xor(mx, o, 8));
        float es = __expf(v[0] - mx) + __expf(v[1] - mx) + __expf(v[2] - mx)
                 + __expf(v[3] - mx) + __expf(v[4] - mx);
#pragma unroll
        for (int o = 4; o; o >>= 1) es += __shfl_xor(es, o, 8);
        float lse = mx + __logf(es);
        float* op = out2 + (size_t)i * F_O + c;
#pragma unroll
        for (int m = 0; m < 5; ++m)
            __builtin_nontemporal_store(v[m] - lse, op + 8 * m);
    }
}

// ---------------- launch ----------------

extern "C" void kernel_launch(void* const* d_in, const int* in_sizes, int n_in,
                              void* d_out, int out_size, void* d_ws, size_t ws_size,
                              hipStream_t stream) {
    const float* x   = (const float*)d_in[0];
    const int* edges = (const int*)d_in[1];
    const float* W1  = (const float*)d_in[2];
    const float* av_s1 = (const float*)d_in[3];
    const float* av_d1 = (const float*)d_in[4];
    const float* b1  = (const float*)d_in[5];
    const float* W2  = (const float*)d_in[6];
    const float* av_s2 = (const float*)d_in[7];
    const float* av_d2 = (const float*)d_in[8];
    const float* b2  = (const float*)d_in[9];
    float* out = (float*)d_out;

    const int N  = in_sizes[0] / F_IN;
    const int E  = in_sizes[1] / 2;
    const int Et = E + N;
    const int NB = (N + 255) >> 8;

    char* p = (char*)d_ws;
    auto alloc = [&](size_t bytes) {
        char* q = p;
        p += (bytes + 255) & ~(size_t)255;
        return (void*)q;
    };
    unsigned short* h1 = (unsigned short*)alloc((size_t)N * F_H * 2);     // f16 [N][64]
    unsigned short* out1h = (unsigned short*)alloc((size_t)N * F_H * 2);  // f16 agg1 output [N][64]
    float* as1    = (float*)alloc((size_t)N * 4);
    float* ad1    = (float*)alloc((size_t)N * 4);
    float* as2    = (float*)alloc((size_t)N * 4);
    float* ad2    = (float*)alloc((size_t)N * 4);
    int* rp       = (int*)alloc((size_t)(N + 1) * 4);
    int* bcnt     = (int*)alloc(NBMAX * 4);
    int* bbase    = (int*)alloc(NBMAX * 4);
    int* bcur     = (int*)alloc(NBMAX * 4);
    unsigned* binned = (unsigned*)alloc((size_t)Et * 4);
    int* csr      = (int*)alloc((size_t)Et * 4);
    unsigned short* WhiT = (unsigned short*)alloc((size_t)F_H * F_IN * 2);
    unsigned short* WloT = (unsigned short*)alloc((size_t)F_H * F_IN * 2);
    unsigned* W2p = (unsigned*)alloc((size_t)F_O * 34 * 4);
    float* wasL   = (float*)alloc(F_H * 4);
    float* wadL   = (float*)alloc(F_H * 4);
    float* csb    = (float*)alloc(2 * 4);
    (void)n_in; (void)out_size; (void)ws_size;

    const int* srcs = edges;
    const int* dsts = edges + E;

    hipMemsetAsync(bcnt, 0, NBMAX * 4, stream);

    k_prep<<<(F_IN * F_H + 255) / 256, 256, 0, stream>>>(W1, WhiT, WloT,
                                                         W2, av_s2, av_d2, b2,
                                                         W2p, wasL, wadL, csb);
    k_binA<<<(Et + 2047) / 2048, 256, 0, stream>>>(dsts, bcnt, E, Et, NB);
    k_binB<<<1, NBMAX, 0, stream>>>(bcnt, bbase, bcur, rp, NB, N, Et);
    k_binC<<<(Et + CHUNK - 1) / CHUNK, 256, 0, stream>>>(srcs, dsts, bcur, binned, E, Et, NB);
    k_binD<<<NB, 256, 0, stream>>>(binned, bbase, bcur, rp, csr, N);

    k_gemm1m<<<(N + 63) / 64, 256, 0, stream>>>(x, WhiT, WloT, av_s1, av_d1, h1, as1, ad1, N);
    int gAgg = (N + 31) / 32;
    k_agg<0><<<gAgg, 256, 0, stream>>>(rp, csr, as1, ad1, (const uint4*)h1,
                                       b1, out1h, wasL, wadL, csb, as2, ad2,
                                       nullptr, nullptr, nullptr, N);
    k_agg<1><<<gAgg, 256, 0, stream>>>(rp, csr, as2, ad2, (const uint4*)out1h,
                                       nullptr, nullptr, nullptr, nullptr, nullptr,
                                       nullptr, nullptr, W2p, b2, out, N);
}